// Round 13
// baseline (446.449 us; speedup 1.0000x reference)
//
#include <hip/hip_runtime.h>
#include <hip/hip_bf16.h>
#include <hip/hip_cooperative_groups.h>
#include <math.h>

namespace coop = cooperative_groups;

#define PI_F 3.14159265358979323846f

#define NS   4
#define CIN  64
#define HH   128
#define WW   128
#define KXN  65          // rfft last-axis size
#define NPIX (HH*WW)
#define MMAT 1600        // CIN*5*5
#define NIT  5           // CG iterations (verified round 12: absmax 0.0378 < 0.0988)
#define SD   136         // LDS halo row stride (16B-aligned)
#define SLAB 167936      // 41*4096 floats, one (n,sl) staging slab

// float offsets in workspace (budget: 11,937,536 floats = 47.75 MB, proven)
#define OFF_SINV 0
#define OFF_E    33280
#define OFF_ER   98816
#define OFF_VR   231936
#define OFF_WB   298496
#define OFF_R    364032      // 4*64*81*64 = 1,327,104 floats -> ends 1,691,136 (layout [n][j][uv][i])
#define OFF_RP   1691136    // Rst2: 4 n * 8 sl * 41 s * 4096 = 5,373,952 floats -> ends 7,065,088
#define OFF_EP   1691136    // k_e partials: 64 c * 4 n * 16384 = 4,194,304 floats (dead before k_gemm)
#define OFF_PP   1691136    // k_pm partials: 2 hh * 4 n * 64 i * 25 (dead after k_rmerge, before CG)
#define OFF_XB   7196160    // bf16 padded copies: 2*4,734,976 ushorts + guard
#define XB0C     4734976    // ushorts per copy (4*64*136*136)
// CG state reuses the (dead-by-then) front-end scratch at offset 0:
#define OFF_DV   0
#define OFF_RV   6400
#define OFF_PV   12800
#define OFF_AP   19200
#define OFF_RV2  25600      // double-buffer for r (iteration parity)
#define OFF_PAPP 32000      // [it*256 + n*64 + j] pAp partials

#define WRED(x) { (x)+=__shfl_down((x),32); (x)+=__shfl_down((x),16); (x)+=__shfl_down((x),8); \
                  (x)+=__shfl_down((x),4);  (x)+=__shfl_down((x),2);  (x)+=__shfl_down((x),1); }

typedef __attribute__((ext_vector_type(8))) short bf16x8;
typedef __attribute__((ext_vector_type(4))) float f32x4;

// ---------------------------------------------------------------------------
// k_sinv v2: per-block 128-entry twiddle table; (ky*(a-2)) & 127 indexing
// (two's-complement AND = exact mod 128 for negative args). Verified r11.
// ---------------------------------------------------------------------------
__global__ __launch_bounds__(256) void k_sinv(const float* __restrict__ dict,
                                              const float* __restrict__ alpha_x,
                                              float* __restrict__ ws) {
  __shared__ float twr[128], twi[128];
  int tid = threadIdx.x;
  if (tid < 128) { float s, c; sincosf(-2.0f*PI_F*(float)tid/128.0f, &s, &c); twr[tid]=c; twi[tid]=s; }
  __syncthreads();
  int idx = blockIdx.x * 256 + tid;
  int n = blockIdx.y;
  if (idx >= HH * KXN) return;
  int ky = idx / KXN, kx = idx % KXN;
  float tr[25], ti[25];
  {
    float eyr[5], eyi[5], exr[5], exi[5];
#pragma unroll
    for (int a = 0; a < 5; ++a) {
      int my = (ky * (a - 2)) & 127;
      eyr[a] = twr[my]; eyi[a] = twi[my];
      int mx = (kx * (a - 2)) & 127;
      exr[a] = twr[mx]; exi[a] = twi[mx];
    }
#pragma unroll
    for (int a = 0; a < 5; ++a)
#pragma unroll
      for (int b = 0; b < 5; ++b) {
        tr[a*5+b] = eyr[a]*exr[b] - eyi[a]*exi[b];
        ti[a*5+b] = eyr[a]*exi[b] + eyi[a]*exr[b];
      }
  }
  const float* dn = dict + n * CIN * 25;
  float S = 0.0f;
  for (int c = 0; c < CIN; ++c) {
    const float* p = dn + c * 25;
    float Dr = 0.0f, Di = 0.0f;
#pragma unroll
    for (int t = 0; t < 25; ++t) { Dr += p[t]*tr[t]; Di += p[t]*ti[t]; }
    S += Dr*Dr + Di*Di;
  }
  float a = alpha_x[n] * (1.0f/64.0f);
  ws[OFF_SINV + (n*HH + ky)*KXN + kx] = 1.0f / (S + a);
}

// ---------------------------------------------------------------------------
// k_e v3: one block = one (channel, n, half-image); slab staged once, then
// pure LDS/VALU sliding-window conv (verified round 6: off the top-5).
// ---------------------------------------------------------------------------
__global__ __launch_bounds__(256) void k_e(const float* __restrict__ x,
                                           const float* __restrict__ dict,
                                           float* __restrict__ ws) {
  __shared__ __align__(16) float xs[68*SD];
  __shared__ float psf_s[25];
  int c = blockIdx.x, n = blockIdx.y, hh = blockIdx.z;
  int tid = threadIdx.x;
  if (tid < 25) psf_s[tid] = dict[(n*CIN + c)*25 + tid];
  const float* Xc = x + (size_t)(n*CIN + c)*NPIX;
  int rbase = hh*64 - 2;
  for (int k = tid; k < 68*132; k += 256) {
    int R = k / 132, C = k - R*132;
    int gh = (rbase + R) & 127;
    int gw = (C - 2) & 127;
    xs[R*SD + C] = Xc[gh*128 + gw];
  }
  __syncthreads();
  int cs = tid & 31, rs = tid >> 5;
  int c0 = cs*4, r0 = rs*8;            // output cols c0..c0+3, rows r0..r0+7
  float w[5][8];
#pragma unroll
  for (int k = 0; k < 4; ++k) {
    f32x4 a = *(const f32x4*)&xs[(r0+k)*SD + c0];
    f32x4 b = *(const f32x4*)&xs[(r0+k)*SD + c0 + 4];
#pragma unroll
    for (int e = 0; e < 4; ++e) { w[k][e] = a[e]; w[k][4+e] = b[e]; }
  }
  float* EPo = ws + OFF_EP + (size_t)(c*4 + n)*NPIX + (size_t)(hh*64 + r0)*128 + c0;
#pragma unroll
  for (int row = 0; row < 8; ++row) {
    int slot = (row + 4) % 5;
    f32x4 a = *(const f32x4*)&xs[(r0+row+4)*SD + c0];
    f32x4 b = *(const f32x4*)&xs[(r0+row+4)*SD + c0 + 4];
#pragma unroll
    for (int e = 0; e < 4; ++e) { w[slot][e] = a[e]; w[slot][4+e] = b[e]; }
    f32x4 acc = (f32x4){0.f,0.f,0.f,0.f};
#pragma unroll
    for (int u = 0; u < 5; ++u)
#pragma unroll
      for (int v = 0; v < 5; ++v) {
        float pv = psf_s[u*5 + v];
#pragma unroll
        for (int p = 0; p < 4; ++p)
          acc[p] += pv * w[(row+u) % 5][p+v];
      }
    *(f32x4*)(EPo + (size_t)row*128) = acc;
  }
}

__global__ __launch_bounds__(256) void k_e2(const float* __restrict__ y,
                                            float* __restrict__ ws) {
  int n = blockIdx.y;
  int p = blockIdx.x*256 + threadIdx.x;     // grid.x = 64 -> covers 16384
  float s = 0.0f;
#pragma unroll 8
  for (int c = 0; c < CIN; ++c) s += ws[OFF_EP + (size_t)(c*4 + n)*NPIX + p];
  ws[OFF_E + n*NPIX + p] = y[n*NPIX + p] - s;
}

// ---------------------------------------------------------------------------
// row DFT
// ---------------------------------------------------------------------------
__global__ __launch_bounds__(256) void k_fft_rows(float* __restrict__ ws) {
  __shared__ float twr[128], twi[128];
  int tid = threadIdx.x;
  if (tid < 128) { float s, c; sincosf(-2.0f*PI_F*(float)tid/128.0f, &s, &c); twr[tid]=c; twi[tid]=s; }
  __syncthreads();
  int idx = blockIdx.x*256 + tid, n = blockIdx.y;
  if (idx >= HH*KXN) return;
  int h = idx / KXN, k = idx % KXN;
  const float* row = ws + OFF_E + (n*HH + h)*WW;
  float sr = 0, si = 0;
  for (int w = 0; w < 128; ++w) {
    int t = (w*k) & 127;
    float v = row[w];
    sr += v*twr[t]; si += v*twi[t];
  }
  float* o = ws + OFF_ER + ((n*HH + h)*KXN + k)*2;
  o[0] = sr; o[1] = si;
}

// ---------------------------------------------------------------------------
// column pipeline: fwd DFT * Sinv, inverse DFT — column stays in LDS
// ---------------------------------------------------------------------------
__global__ __launch_bounds__(128) void k_fft_colpipe(float* __restrict__ ws) {
  __shared__ float twr[128], twi[128];
  __shared__ float ecr[128], eci[128];
  __shared__ float ewr[128], ewi[128];
  int tid = threadIdx.x;
  int kx = blockIdx.x, n = blockIdx.y;
  { float s, c; sincosf(-2.0f*PI_F*(float)tid/128.0f, &s, &c); twr[tid]=c; twi[tid]=s; }
  const float* Er = ws + OFF_ER + (size_t)n*HH*KXN*2;
  ecr[tid] = Er[(tid*KXN + kx)*2];
  eci[tid] = Er[(tid*KXN + kx)*2 + 1];
  __syncthreads();
  {
    int ky = tid;
    float sr = 0, si = 0;
    for (int h = 0; h < 128; ++h) {
      int t = (h*ky) & 127;
      float ar = ecr[h], ai = eci[h];
      sr += ar*twr[t] - ai*twi[t];
      si += ar*twi[t] + ai*twr[t];
    }
    float sv = ws[OFF_SINV + (n*HH + ky)*KXN + kx];
    ewr[ky] = sr*sv; ewi[ky] = si*sv;
  }
  __syncthreads();
  {
    int h = tid;
    float sr = 0, si = 0;
    for (int ky = 0; ky < 128; ++ky) {
      int t = (h*ky) & 127;
      float ar = ewr[ky], ai = ewi[ky];
      sr += ar*twr[t] + ai*twi[t];
      si += ai*twr[t] - ar*twi[t];
    }
    float* o = ws + OFF_VR + ((n*HH + h)*KXN + kx)*2;
    o[0] = sr; o[1] = si;
  }
}

__global__ __launch_bounds__(256) void k_ifft_rows(float* __restrict__ ws) {
  __shared__ float twr[128], twi[128];
  int tid = threadIdx.x;
  if (tid < 128) { float s, c; sincosf(-2.0f*PI_F*(float)tid/128.0f, &s, &c); twr[tid]=c; twi[tid]=s; }
  __syncthreads();
  int idx = blockIdx.x*256 + tid, n = blockIdx.y;
  int h = idx >> 7, w = idx & 127;
  const float* Vr = ws + OFF_VR + (size_t)n*HH*KXN*2;
  float s = 0.0f;
  for (int kx = 0; kx <= 64; ++kx) {
    int t = (w*kx) & 127;
    float ar = Vr[(h*KXN + kx)*2], ai = Vr[(h*KXN + kx)*2 + 1];
    float re = ar*twr[t] + ai*twi[t];
    s += (kx == 0 || kx == 64) ? re : 2.0f*re;
  }
  ws[OFF_WB + (n*HH + h)*WW + w] = s * (1.0f/16384.0f);
}

// ---------------------------------------------------------------------------
// k_xnew v2: slab+slide correlate-back (verified round 9).
// ---------------------------------------------------------------------------
__global__ __launch_bounds__(256) void k_xnew(const float* __restrict__ x,
                                              const float* __restrict__ dict,
                                              const float* __restrict__ ws,
                                              float* __restrict__ out) {
  __shared__ __align__(16) float xs[68*SD];
  __shared__ float psf_s[25];
  int c = blockIdx.x, n = blockIdx.y, hh = blockIdx.z;
  int tid = threadIdx.x;
  if (tid < 25) psf_s[tid] = dict[(n*CIN + c)*25 + 24 - tid];   // flipped kernel
  const float* Wb = ws + OFF_WB + (size_t)n*NPIX;
  int rbase = hh*64 - 2;
  for (int k = tid; k < 68*132; k += 256) {
    int R = k / 132, C = k - R*132;
    int gh = (rbase + R) & 127;
    int gw = (C - 2) & 127;
    xs[R*SD + C] = Wb[gh*128 + gw];
  }
  __syncthreads();
  int cs = tid & 31, rs = tid >> 5;
  int c0 = cs*4, r0 = rs*8;
  float w[5][8];
#pragma unroll
  for (int k = 0; k < 4; ++k) {
    f32x4 a = *(const f32x4*)&xs[(r0+k)*SD + c0];
    f32x4 b = *(const f32x4*)&xs[(r0+k)*SD + c0 + 4];
#pragma unroll
    for (int e = 0; e < 4; ++e) { w[k][e] = a[e]; w[k][4+e] = b[e]; }
  }
  const float* Xc = x   + (size_t)(n*CIN + c)*NPIX + (size_t)(hh*64 + r0)*128 + c0;
  float*       Oc = out + (size_t)(n*CIN + c)*NPIX + (size_t)(hh*64 + r0)*128 + c0;
#pragma unroll
  for (int row = 0; row < 8; ++row) {
    int slot = (row + 4) % 5;
    f32x4 a = *(const f32x4*)&xs[(r0+row+4)*SD + c0];
    f32x4 b = *(const f32x4*)&xs[(r0+row+4)*SD + c0 + 4];
#pragma unroll
    for (int e = 0; e < 4; ++e) { w[slot][e] = a[e]; w[slot][4+e] = b[e]; }
    f32x4 acc = *(const f32x4*)(Xc + (size_t)row*128);
#pragma unroll
    for (int u = 0; u < 5; ++u)
#pragma unroll
      for (int v = 0; v < 5; ++v) {
        float pv = psf_s[u*5 + v];
#pragma unroll
        for (int p = 0; p < 4; ++p)
          acc[p] += pv * w[(row+u) % 5][p+v];
      }
    *(f32x4*)(Oc + (size_t)row*128) = acc;
  }
}

// ---------------------------------------------------------------------------
// k_pad: x_new -> zero-padded bf16 image, two copies (copy1 offset by one
// element so odd-v shifted reads are dword-aligned).
// ---------------------------------------------------------------------------
__global__ __launch_bounds__(256) void k_pad(const float* __restrict__ xn,
                                             float* __restrict__ ws) {
  ushort* xb0 = (ushort*)(ws + OFF_XB);
  ushort* xb1 = xb0 + XB0C;
  int ch = blockIdx.y;
  int idx = blockIdx.x*256 + threadIdx.x;
  if (ch == 0 && idx == 0) xb1[0] = 0;
  if (idx >= 136*136) return;
  int hp = idx / 136, wp = idx % 136;
  float v = 0.0f;
  if (hp >= 4 && hp < 132 && wp >= 4 && wp < 132)
    v = xn[(size_t)ch*NPIX + (hp-4)*128 + (wp-4)];
  __hip_bfloat16 b = __float2bfloat16(v);
  ushort bits = *(ushort*)&b;
  size_t o = (size_t)ch*18496 + idx;
  xb0[o] = bits;
  xb1[o + 1] = bits;
}

// ---------------------------------------------------------------------------
// k_gemm v8 (verified 44-46us; v9 dbuf and v10 32x32 both regressed).
// Bound by barrier-synchronized staging latency; staging decode
// (4 rows x 256B contiguous per instr) is the critical property.
// ---------------------------------------------------------------------------
__global__ __launch_bounds__(256, 3) void k_gemm(float* __restrict__ ws) {
  __shared__ __align__(16) ushort sA0[64*128];
  __shared__ __align__(16) ushort sA1[64*128];
  __shared__ __align__(16) ushort sB [64*128];

  const ushort* xb0 = (const ushort*)(ws + OFF_XB);
  const ushort* xb1 = xb0 + XB0C;
  int fid = blockIdx.x;
  int xcd = fid & 7, l = fid >> 3;        // l in [0,84)
  int nn = xcd & 3, hi = xcd >> 2;        // 2 XCDs per n; hi = sl parity
  int g = l % 21, m = l / 21;             // m in [0,4)
  int sl = m*2 + hi;                      // [0,8), K-slice of 2048

  int tid = threadIdx.x;
  int wv = tid >> 6, lane = tid & 63;
  int l16 = lane & 15, quad = lane >> 4;
  int lr = lane >> 4, lc = lane & 15;     // stage decode (4 rows x 16 cols)

  // shifts handled by this block
  int sidx0 = 2*g;
  int sidx1 = 2*g + 1;
  int sval1 = (sidx1 <= 40);
  if (sidx1 > 40) sidx1 = 40;
  int uv0 = sidx0 + 40, uv1 = sidx1 + 40;
  int u0 = uv0 / 9, v0 = uv0 % 9;
  int u1 = uv1 / 9, v1 = uv1 % 9;

  size_t chanBase = (size_t)(nn*64) * 18496;
  int ridx0 = sl * 16;                     // first image row of this K-slice
  // per-row-start pointers (element units), advanced by 136 per round
  const ushort* pB  = xb0 + chanBase + 548 + (size_t)ridx0*136;   // row 4, col 4
  size_t a0e = chanBase + (size_t)(u0 + ridx0)*136 + v0;
  size_t a1e = chanBase + (size_t)(u1 + ridx0)*136 + v1;
  const ushort* pA0 = (v0 & 1) ? (xb1 + a0e + 1) : (xb0 + a0e);
  const ushort* pA1 = (v1 & 1) ? (xb1 + a1e + 1) : (xb0 + a1e);

  f32x4 acc[2][4];
#pragma unroll
  for (int s = 0; s < 2; ++s)
#pragma unroll
    for (int jt = 0; jt < 4; ++jt) acc[s][jt] = (f32x4){0.f,0.f,0.f,0.f};

  for (int r = 0; r < 16; ++r) {
    if (r) __syncthreads();
    // ---- stage 3 tiles: wave wv covers rows wv*16 .. wv*16+15 ----
#pragma unroll
    for (int c = 0; c < 4; ++c) {
      int row = wv*16 + c*4 + lr;
      int sw = ((lc ^ (row & 15)) * 8);
      size_t goff = (size_t)row * 18496 + (size_t)lc * 8;
      {  // B: 8B-aligned source -> two uint2 loads
        const uint2* p = (const uint2*)(pB + goff);
        uint2 b0 = p[0], b1 = p[1];
        *(uint2*)&sB[row*128 + sw]     = b0;
        *(uint2*)&sB[row*128 + sw + 4] = b1;
      }
      {  // A0: 4B-aligned source -> four dword loads
        const uint* p = (const uint*)(pA0 + goff);
        uint4 v4; v4.x = p[0]; v4.y = p[1]; v4.z = p[2]; v4.w = p[3];
        *(uint4*)&sA0[row*128 + sw] = v4;
      }
      {  // A1
        const uint* p = (const uint*)(pA1 + goff);
        uint4 v4; v4.x = p[0]; v4.y = p[1]; v4.z = p[2]; v4.w = p[3];
        *(uint4*)&sA1[row*128 + sw] = v4;
      }
    }
    __syncthreads();
    // ---- compute 4 kt (K=32 each) ----
#pragma unroll
    for (int kt = 0; kt < 4; ++kt) {
      int c16 = kt*4 + quad;
      int sw = ((c16 ^ l16) * 8);
      bf16x8 af0 = *(const bf16x8*)&sA0[(wv*16 + l16)*128 + sw];
      bf16x8 af1 = *(const bf16x8*)&sA1[(wv*16 + l16)*128 + sw];
      bf16x8 bf[4];
#pragma unroll
      for (int jt = 0; jt < 4; ++jt)
        bf[jt] = *(const bf16x8*)&sB[(jt*16 + l16)*128 + sw];
#pragma unroll
      for (int jt = 0; jt < 4; ++jt) {
        acc[0][jt] = __builtin_amdgcn_mfma_f32_16x16x32_bf16(af0, bf[jt], acc[0][jt], 0, 0, 0);
        acc[1][jt] = __builtin_amdgcn_mfma_f32_16x16x32_bf16(af1, bf[jt], acc[1][jt], 0, 0, 0);
      }
    }
    pB += 136; pA0 += 136; pA1 += 136;
  }

  // ---- epilogue: plain vector stores into slice-private staging ----
  int io = wv*16 + quad*4;
  {
    float* dst = ws + OFF_RP + (((size_t)nn*8 + sl)*41 + sidx0)*4096;
#pragma unroll
    for (int jt = 0; jt < 4; ++jt) {
      int jout = jt*16 + l16;
      *reinterpret_cast<f32x4*>(dst + jout*64 + io) = acc[0][jt];
    }
  }
  if (sval1) {
    float* dst = ws + OFF_RP + (((size_t)nn*8 + sl)*41 + sidx1)*4096;
#pragma unroll
    for (int jt = 0; jt < 4; ++jt) {
      int jout = jt*16 + l16;
      *reinterpret_cast<f32x4*>(dst + jout*64 + io) = acc[1][jt];
    }
  }
}

// ---------------------------------------------------------------------------
// k_rsumtrans: per (n,s) plane, sum 8 K-slices (coalesced) -> P (slot 0)
// and 64x64 transpose -> PT (slot 1). Verified round 7.
// ---------------------------------------------------------------------------
__global__ __launch_bounds__(256) void k_rsumtrans(float* __restrict__ ws) {
  __shared__ float tile[64][65];
  int s = blockIdx.x, n = blockIdx.y;
  float* base0 = ws + OFF_RP + ((size_t)n*8)*SLAB + (size_t)s*4096;
  int t = threadIdx.x;
#pragma unroll
  for (int p = 0; p < 4; ++p) {
    int vidx = p*256 + t;                 // 0..1023, 16 f32x4 per row
    int row = vidx >> 4, c0 = (vidx & 15)*4;
    f32x4 sum = (f32x4){0.f,0.f,0.f,0.f};
#pragma unroll
    for (int sl = 0; sl < 8; ++sl)
      sum += *(const f32x4*)(base0 + (size_t)sl*SLAB + row*64 + c0);
    *(f32x4*)(base0 + row*64 + c0) = sum;           // P, slot 0
    tile[row][c0]   = sum[0]; tile[row][c0+1] = sum[1];
    tile[row][c0+2] = sum[2]; tile[row][c0+3] = sum[3];
  }
  __syncthreads();
  float* PT = base0 + SLAB;                          // slot 1
#pragma unroll
  for (int p = 0; p < 4; ++p) {
    int vidx = p*256 + t;
    int row = vidx >> 4, c0 = (vidx & 15)*4;
    f32x4 o;
#pragma unroll
    for (int e = 0; e < 4; ++e) o[e] = tile[c0+e][row];
    *(f32x4*)(PT + row*64 + c0) = o;
  }
}

// ---------------------------------------------------------------------------
// k_rmerge v4: R relaid as [n][j][uv][i] so CG's per-lane-i reads are
// coalesced. Verified round 8.
// ---------------------------------------------------------------------------
__global__ __launch_bounds__(256) void k_rmerge(float* __restrict__ ws) {
  int j = blockIdx.x, n = blockIdx.y;
  const float* P  = ws + OFF_RP + ((size_t)n*8 + 0)*SLAB;
  const float* PT = ws + OFF_RP + ((size_t)n*8 + 1)*SLAB;
  float* out = ws + OFF_R + ((size_t)(n*64 + j))*81*64;
  int t = threadIdx.x;
  for (int k = t; k < 81*64; k += 256) {
    int uv = k >> 6, i = k & 63;
    float v = (uv >= 40) ? P [(size_t)(uv-40)*4096 + j*64 + i]
                         : PT[(size_t)(40-uv)*4096 + j*64 + i];
    out[k] = v;
  }
}

// ---------------------------------------------------------------------------
// k_pm v3: slab-staged sliding-window XtY (verified round 6: off the top-5).
// ---------------------------------------------------------------------------
__global__ __launch_bounds__(256) void k_pm(const float* __restrict__ xn,
                                            const float* __restrict__ y,
                                            float* __restrict__ ws) {
  __shared__ __align__(16) float xs[68*SD];
  __shared__ float red_s[4][25];
  int i = blockIdx.x, n = blockIdx.y, hh = blockIdx.z;
  int tid = threadIdx.x;
  const float* Xi = xn + (size_t)(n*CIN + i)*NPIX;
  int rbase = hh*64 - 2;
  for (int k = tid; k < 68*132; k += 256) {
    int R = k / 132, C = k - R*132;
    int hr = rbase + R, wc = C - 2;
    float v = 0.0f;
    if (hr >= 0 && hr < 128 && wc >= 0 && wc < 128) v = Xi[hr*128 + wc];
    xs[R*SD + C] = v;
  }
  __syncthreads();
  int cs = tid & 31, rs = tid >> 5;
  int c0 = cs*4, r0 = rs*8;
  float w[5][8];
#pragma unroll
  for (int k = 0; k < 4; ++k) {
    f32x4 a = *(const f32x4*)&xs[(r0+k)*SD + c0];
    f32x4 b = *(const f32x4*)&xs[(r0+k)*SD + c0 + 4];
#pragma unroll
    for (int e = 0; e < 4; ++e) { w[k][e] = a[e]; w[k][4+e] = b[e]; }
  }
  float acc[25];
#pragma unroll
  for (int t = 0; t < 25; ++t) acc[t] = 0.0f;
  const float* yp = y + (size_t)n*NPIX + (size_t)(hh*64 + r0)*128 + c0;
#pragma unroll
  for (int row = 0; row < 8; ++row) {
    int slot = (row + 4) % 5;
    f32x4 a = *(const f32x4*)&xs[(r0+row+4)*SD + c0];
    f32x4 b = *(const f32x4*)&xs[(r0+row+4)*SD + c0 + 4];
#pragma unroll
    for (int e = 0; e < 4; ++e) { w[slot][e] = a[e]; w[slot][4+e] = b[e]; }
    f32x4 yv = *(const f32x4*)(yp + (size_t)row*128);
#pragma unroll
    for (int u = 0; u < 5; ++u)
#pragma unroll
      for (int v = 0; v < 5; ++v) {
#pragma unroll
        for (int p = 0; p < 4; ++p)
          acc[u*5+v] += w[(row+u) % 5][p+v] * yv[p];
      }
  }
  int lane = tid & 63, wv = tid >> 6;
#pragma unroll
  for (int t = 0; t < 25; ++t) {
    float v = acc[t];
    WRED(v);
    if (lane == 0) red_s[wv][t] = v;
  }
  __syncthreads();
  if (tid < 25) {
    float s = red_s[0][tid] + red_s[1][tid] + red_s[2][tid] + red_s[3][tid];
    ws[OFF_PP + ((size_t)(hh*4 + n)*64 + i)*25 + tid] = s;
  }
}

__global__ __launch_bounds__(64) void k_pm2(const float* __restrict__ dict,
                                            const float* __restrict__ alpha_d,
                                            const float* __restrict__ regp,
                                            float* __restrict__ ws) {
  int i = blockIdx.x, n = blockIdx.y, t = threadIdx.x;
  if (t >= 25) return;
  float s = 0.0f;
#pragma unroll
  for (int tg = 0; tg < 2; ++tg) s += ws[OFF_PP + ((size_t)(tg*4 + n)*64 + i)*25 + t];
  float ad = alpha_d[n] * 16384.0f * regp[0] * (1.0f/1600.0f);
  float val = s + ad * dict[(n*CIN + i)*25 + t];
  int idx = n*MMAT + i*25 + t;
  ws[OFF_RV + idx] = val;
  ws[OFF_PV + idx] = val;
}

// ---------------------------------------------------------------------------
// k_cg_all (round 13): the entire CG solve in ONE cooperative kernel.
// grid.sync() replaces the 5 launch boundaries of the previous
// cg_first + 5x cg_step chain; loop bodies are verbatim the verified code.
// Cross-sync dataflow (rsrc parity buffers, AP, PAPP[it]) identical to the
// multi-launch version. All blocks co-resident: 256 blocks x 256 thr,
// 8.6KB LDS. The 'last' branch returns uniformly before any further sync.
// ---------------------------------------------------------------------------
__global__ __launch_bounds__(256) void k_cg_all(float* __restrict__ ws,
                                                float* __restrict__ out,
                                                const float* __restrict__ alpha_d,
                                                const float* __restrict__ regp) {
  coop::grid_group gg = coop::this_grid();
  __shared__ float vv[MMAT];
  __shared__ float red_s[9];
  __shared__ float part[25][66];
  int n = blockIdx.y, j = blockIdx.x, tid = threadIdx.x;
  int lane = tid & 63, wvi = tid >> 6;
  int i = tid & 63, qq = tid >> 6;
  const float* Rj = ws + OFF_R + ((size_t)(n*CIN + j))*81*64;
  float reg = alpha_d[n] * 16384.0f * regp[0] * (1.0f/1600.0f);

  // ---------- phase 0: cg_first (Ap0 + pAp0 partials) ----------
  for (int t = tid; t < MMAT; t += 256) vv[t] = ws[OFF_PV + n*MMAT + t];
  __syncthreads();
  {
    const float* vi = &vv[i*25];
#pragma unroll
    for (int s6 = 0; s6 < 7; ++s6) {
      int ac = qq + 4*s6;
      if (ac < 25) {
        int a = ac/5, c = ac%5;
        float s = 0.0f;
#pragma unroll
        for (int b = 0; b < 5; ++b)
#pragma unroll
          for (int d = 0; d < 5; ++d)
            s += Rj[((4+b-a)*9 + (4+d-c))*64 + i] * vi[b*5+d];
        part[ac][i] = s;
      }
    }
    __syncthreads();
    float contrib = 0.0f;
    if (tid < 25) {
      float s = 0.0f;
      for (int t = 0; t < 64; ++t) s += part[tid][t];
      s += reg * vv[j*25 + tid];
      ws[OFF_AP + n*MMAT + j*25 + tid] = s;
      contrib = s * vv[j*25 + tid];
    }
    if (tid < 64) {
      WRED(contrib);
      if (tid == 0) ws[OFF_PAPP + 0*256 + n*64 + j] = contrib;
    }
  }
  gg.sync();

  // ---------- NIT fused steps ----------
  for (int it = 0; it < NIT; ++it) {
    const float* rsrc = ws + ((it & 1) ? OFF_RV2 : OFF_RV) + n*MMAT;
    float*       rdst = ws + ((it & 1) ? OFF_RV  : OFF_RV2) + n*MMAT;

    float rold[7], apv[7];
    float rrp = 0.0f;
#pragma unroll
    for (int t = 0; t < 7; ++t) {
      int idx = tid + 256*t;
      rold[t] = 0.0f; apv[t] = 0.0f;
      if (idx < MMAT) {
        rold[t] = rsrc[idx];
        apv[t]  = ws[OFF_AP + n*MMAT + idx];
        rrp += rold[t]*rold[t];
      }
    }
    WRED(rrp);
    if (lane == 0) red_s[wvi] = rrp;
    float pp = (tid < 64) ? ws[OFF_PAPP + it*256 + n*64 + tid] : 0.0f;
    if (tid < 64) { WRED(pp); if (tid == 0) red_s[4] = pp; }
    __syncthreads();
    float rr_old = red_s[0] + red_s[1] + red_s[2] + red_s[3];
    float alpha = rr_old / (red_s[4] + 1e-30f);

    if (it == NIT-1) {                      // uniform: all blocks exit together
      if (tid < 25) {
        int idx = n*MMAT + j*25 + tid;
        float dv = ws[OFF_DV + idx] + alpha * ws[OFF_PV + idx];
        out[4194304 + n*MMAT + j*25 + tid] = dv;
      }
      return;
    }

    float rrnp = 0.0f;
#pragma unroll
    for (int t = 0; t < 7; ++t) {
      int idx = tid + 256*t;
      if (idx < MMAT) {
        float rn = rold[t] - alpha * apv[t];
        vv[idx] = rn;
        rrnp += rn*rn;
      }
    }
    WRED(rrnp);
    __syncthreads();                         // vv complete
    if (lane == 0) red_s[5 + wvi] = rrnp;
    __syncthreads();
    float rr_new = red_s[5] + red_s[6] + red_s[7] + red_s[8];
    float beta = rr_new / (rr_old + 1e-30f);

    const float* vi = &vv[i*25];
#pragma unroll
    for (int s6 = 0; s6 < 7; ++s6) {
      int ac = qq + 4*s6;
      if (ac < 25) {
        int a = ac/5, c = ac%5;
        float s = 0.0f;
#pragma unroll
        for (int b = 0; b < 5; ++b)
#pragma unroll
          for (int d = 0; d < 5; ++d)
            s += Rj[((4+b-a)*9 + (4+d-c))*64 + i] * vi[b*5+d];
        part[ac][i] = s;
      }
    }
    __syncthreads();
    float contrib = 0.0f;
    if (tid < 25) {
      float s = 0.0f;
      for (int t = 0; t < 64; ++t) s += part[tid][t];
      float rn_seg = vv[j*25 + tid];
      s += reg * rn_seg;
      int idx = n*MMAT + j*25 + tid;
      float p_old = ws[OFF_PV + idx];
      float dv = ws[OFF_DV + idx] + alpha * p_old;
      float pn  = rn_seg + beta * p_old;
      float apn = s + beta * ws[OFF_AP + idx];
      ws[OFF_DV + idx] = dv;
      ws[OFF_PV + idx] = pn;
      ws[OFF_AP + idx] = apn;
      rdst[j*25 + tid] = rn_seg;
      contrib = pn * apn;
    }
    if (tid < 64) {
      WRED(contrib);
      if (tid == 0) ws[OFF_PAPP + (it+1)*256 + n*64 + j] = contrib;
    }
    gg.sync();
  }
}

// ---------------------------------------------------------------------------
extern "C" void kernel_launch(void* const* d_in, const int* in_sizes, int n_in,
                              void* d_out, int out_size, void* d_ws, size_t ws_size,
                              hipStream_t stream) {
  (void)in_sizes; (void)n_in; (void)out_size; (void)ws_size;
  const float* x    = (const float*)d_in[0];
  const float* dict = (const float*)d_in[1];
  const float* y    = (const float*)d_in[2];
  const float* ax   = (const float*)d_in[3];
  const float* ad   = (const float*)d_in[4];
  const float* regp = (const float*)d_in[5];
  float* out = (float*)d_out;
  float* ws  = (float*)d_ws;

  dim3 b256(256);
  k_sinv<<<dim3(33,4), b256, 0, stream>>>(dict, ax, ws);
  k_e<<<dim3(64,4,2), b256, 0, stream>>>(x, dict, ws);
  k_e2<<<dim3(64,4), b256, 0, stream>>>(y, ws);
  k_fft_rows<<<dim3(33,4), b256, 0, stream>>>(ws);
  k_fft_colpipe<<<dim3(65,4), dim3(128), 0, stream>>>(ws);
  k_ifft_rows<<<dim3(64,4), b256, 0, stream>>>(ws);
  k_xnew<<<dim3(64,4,2), b256, 0, stream>>>(x, dict, ws, out);

  // ---- R via MFMA: pad, LDS-staged shift-GEMM, slice-sum+transpose, merge
  k_pad<<<dim3(73,256), b256, 0, stream>>>(out, ws);
  k_gemm<<<dim3(672), b256, 0, stream>>>(ws);
  k_rsumtrans<<<dim3(41,4), b256, 0, stream>>>(ws);
  k_rmerge<<<dim3(64,4), b256, 0, stream>>>(ws);

  k_pm<<<dim3(64,4,2), b256, 0, stream>>>(out, y, ws);
  k_pm2<<<dim3(64,4), dim3(64), 0, stream>>>(dict, ad, regp, ws);

  // ---- CG: single cooperative kernel (grid.sync at old launch boundaries)
  {
    void* cgArgs[] = { (void*)&ws, (void*)&out, (void*)&ad, (void*)&regp };
    hipLaunchCooperativeKernel(reinterpret_cast<void*>(k_cg_all),
                               dim3(64,4), dim3(256), cgArgs, 0, stream);
  }
}

// Round 14
// 266.405 us; speedup vs baseline: 1.6758x; 1.6758x over previous
//
#include <hip/hip_runtime.h>
#include <hip/hip_bf16.h>
#include <math.h>

#define PI_F 3.14159265358979323846f

#define NS   4
#define CIN  64
#define HH   128
#define WW   128
#define KXN  65          // rfft last-axis size
#define NPIX (HH*WW)
#define MMAT 1600        // CIN*5*5
#define NIT  5           // CG iterations (verified round 12: absmax 0.0378 < 0.0988)
#define SD   136         // LDS halo row stride (16B-aligned)
#define SLAB 167936      // 41*4096 floats, one (n,sl) staging slab

// float offsets in workspace (budget: 11,937,536 floats = 47.75 MB, proven)
#define OFF_SINV 0
#define OFF_E    33280
#define OFF_ER   98816
#define OFF_VR   231936
#define OFF_WB   298496
#define OFF_R    364032      // 4*64*81*64 = 1,327,104 floats -> ends 1,691,136 (layout [n][j][uv][i])
#define OFF_RP   1691136    // Rst2: 4 n * 8 sl * 41 s * 4096 = 5,373,952 floats -> ends 7,065,088
#define OFF_EP   1691136    // k_e partials: 64 c * 4 n * 16384 = 4,194,304 floats (dead before k_gemm)
#define OFF_PP   1691136    // k_pm partials: 2 hh * 4 n * 64 i * 25 (dead after k_rmerge, before CG)
#define OFF_XB   7196160    // bf16 padded copies: 2*4,734,976 ushorts + guard
#define XB0C     4734976    // ushorts per copy (4*64*136*136)
// CG state reuses the (dead-by-then) front-end scratch at offset 0:
#define OFF_DV   0
#define OFF_RV   6400
#define OFF_PV   12800
#define OFF_AP   19200
#define OFF_RV2  25600      // double-buffer for r (iteration parity)
#define OFF_PAPP 32000      // [it*256 + n*64 + j] pAp partials

#define WRED(x) { (x)+=__shfl_down((x),32); (x)+=__shfl_down((x),16); (x)+=__shfl_down((x),8); \
                  (x)+=__shfl_down((x),4);  (x)+=__shfl_down((x),2);  (x)+=__shfl_down((x),1); }

typedef __attribute__((ext_vector_type(8))) short bf16x8;
typedef __attribute__((ext_vector_type(4))) float f32x4;

// ---------------------------------------------------------------------------
// k_sinv v2: per-block 128-entry twiddle table; (ky*(a-2)) & 127 indexing
// (two's-complement AND = exact mod 128 for negative args). Verified r11.
// ---------------------------------------------------------------------------
__global__ __launch_bounds__(256) void k_sinv(const float* __restrict__ dict,
                                              const float* __restrict__ alpha_x,
                                              float* __restrict__ ws) {
  __shared__ float twr[128], twi[128];
  int tid = threadIdx.x;
  if (tid < 128) { float s, c; sincosf(-2.0f*PI_F*(float)tid/128.0f, &s, &c); twr[tid]=c; twi[tid]=s; }
  __syncthreads();
  int idx = blockIdx.x * 256 + tid;
  int n = blockIdx.y;
  if (idx >= HH * KXN) return;
  int ky = idx / KXN, kx = idx % KXN;
  float tr[25], ti[25];
  {
    float eyr[5], eyi[5], exr[5], exi[5];
#pragma unroll
    for (int a = 0; a < 5; ++a) {
      int my = (ky * (a - 2)) & 127;
      eyr[a] = twr[my]; eyi[a] = twi[my];
      int mx = (kx * (a - 2)) & 127;
      exr[a] = twr[mx]; exi[a] = twi[mx];
    }
#pragma unroll
    for (int a = 0; a < 5; ++a)
#pragma unroll
      for (int b = 0; b < 5; ++b) {
        tr[a*5+b] = eyr[a]*exr[b] - eyi[a]*exi[b];
        ti[a*5+b] = eyr[a]*exi[b] + eyi[a]*exr[b];
      }
  }
  const float* dn = dict + n * CIN * 25;
  float S = 0.0f;
  for (int c = 0; c < CIN; ++c) {
    const float* p = dn + c * 25;
    float Dr = 0.0f, Di = 0.0f;
#pragma unroll
    for (int t = 0; t < 25; ++t) { Dr += p[t]*tr[t]; Di += p[t]*ti[t]; }
    S += Dr*Dr + Di*Di;
  }
  float a = alpha_x[n] * (1.0f/64.0f);
  ws[OFF_SINV + (n*HH + ky)*KXN + kx] = 1.0f / (S + a);
}

// ---------------------------------------------------------------------------
// k_e v3: one block = one (channel, n, half-image); slab staged once, then
// pure LDS/VALU sliding-window conv (verified round 6: off the top-5).
// ---------------------------------------------------------------------------
__global__ __launch_bounds__(256) void k_e(const float* __restrict__ x,
                                           const float* __restrict__ dict,
                                           float* __restrict__ ws) {
  __shared__ __align__(16) float xs[68*SD];
  __shared__ float psf_s[25];
  int c = blockIdx.x, n = blockIdx.y, hh = blockIdx.z;
  int tid = threadIdx.x;
  if (tid < 25) psf_s[tid] = dict[(n*CIN + c)*25 + tid];
  const float* Xc = x + (size_t)(n*CIN + c)*NPIX;
  int rbase = hh*64 - 2;
  for (int k = tid; k < 68*132; k += 256) {
    int R = k / 132, C = k - R*132;
    int gh = (rbase + R) & 127;
    int gw = (C - 2) & 127;
    xs[R*SD + C] = Xc[gh*128 + gw];
  }
  __syncthreads();
  int cs = tid & 31, rs = tid >> 5;
  int c0 = cs*4, r0 = rs*8;            // output cols c0..c0+3, rows r0..r0+7
  float w[5][8];
#pragma unroll
  for (int k = 0; k < 4; ++k) {
    f32x4 a = *(const f32x4*)&xs[(r0+k)*SD + c0];
    f32x4 b = *(const f32x4*)&xs[(r0+k)*SD + c0 + 4];
#pragma unroll
    for (int e = 0; e < 4; ++e) { w[k][e] = a[e]; w[k][4+e] = b[e]; }
  }
  float* EPo = ws + OFF_EP + (size_t)(c*4 + n)*NPIX + (size_t)(hh*64 + r0)*128 + c0;
#pragma unroll
  for (int row = 0; row < 8; ++row) {
    int slot = (row + 4) % 5;
    f32x4 a = *(const f32x4*)&xs[(r0+row+4)*SD + c0];
    f32x4 b = *(const f32x4*)&xs[(r0+row+4)*SD + c0 + 4];
#pragma unroll
    for (int e = 0; e < 4; ++e) { w[slot][e] = a[e]; w[slot][4+e] = b[e]; }
    f32x4 acc = (f32x4){0.f,0.f,0.f,0.f};
#pragma unroll
    for (int u = 0; u < 5; ++u)
#pragma unroll
      for (int v = 0; v < 5; ++v) {
        float pv = psf_s[u*5 + v];
#pragma unroll
        for (int p = 0; p < 4; ++p)
          acc[p] += pv * w[(row+u) % 5][p+v];
      }
    *(f32x4*)(EPo + (size_t)row*128) = acc;
  }
}

__global__ __launch_bounds__(256) void k_e2(const float* __restrict__ y,
                                            float* __restrict__ ws) {
  int n = blockIdx.y;
  int p = blockIdx.x*256 + threadIdx.x;     // grid.x = 64 -> covers 16384
  float s = 0.0f;
#pragma unroll 8
  for (int c = 0; c < CIN; ++c) s += ws[OFF_EP + (size_t)(c*4 + n)*NPIX + p];
  ws[OFF_E + n*NPIX + p] = y[n*NPIX + p] - s;
}

// ---------------------------------------------------------------------------
// row DFT
// ---------------------------------------------------------------------------
__global__ __launch_bounds__(256) void k_fft_rows(float* __restrict__ ws) {
  __shared__ float twr[128], twi[128];
  int tid = threadIdx.x;
  if (tid < 128) { float s, c; sincosf(-2.0f*PI_F*(float)tid/128.0f, &s, &c); twr[tid]=c; twi[tid]=s; }
  __syncthreads();
  int idx = blockIdx.x*256 + tid, n = blockIdx.y;
  if (idx >= HH*KXN) return;
  int h = idx / KXN, k = idx % KXN;
  const float* row = ws + OFF_E + (n*HH + h)*WW;
  float sr = 0, si = 0;
  for (int w = 0; w < 128; ++w) {
    int t = (w*k) & 127;
    float v = row[w];
    sr += v*twr[t]; si += v*twi[t];
  }
  float* o = ws + OFF_ER + ((n*HH + h)*KXN + k)*2;
  o[0] = sr; o[1] = si;
}

// ---------------------------------------------------------------------------
// column pipeline: fwd DFT * Sinv, inverse DFT — column stays in LDS
// ---------------------------------------------------------------------------
__global__ __launch_bounds__(128) void k_fft_colpipe(float* __restrict__ ws) {
  __shared__ float twr[128], twi[128];
  __shared__ float ecr[128], eci[128];
  __shared__ float ewr[128], ewi[128];
  int tid = threadIdx.x;
  int kx = blockIdx.x, n = blockIdx.y;
  { float s, c; sincosf(-2.0f*PI_F*(float)tid/128.0f, &s, &c); twr[tid]=c; twi[tid]=s; }
  const float* Er = ws + OFF_ER + (size_t)n*HH*KXN*2;
  ecr[tid] = Er[(tid*KXN + kx)*2];
  eci[tid] = Er[(tid*KXN + kx)*2 + 1];
  __syncthreads();
  {
    int ky = tid;
    float sr = 0, si = 0;
    for (int h = 0; h < 128; ++h) {
      int t = (h*ky) & 127;
      float ar = ecr[h], ai = eci[h];
      sr += ar*twr[t] - ai*twi[t];
      si += ar*twi[t] + ai*twr[t];
    }
    float sv = ws[OFF_SINV + (n*HH + ky)*KXN + kx];
    ewr[ky] = sr*sv; ewi[ky] = si*sv;
  }
  __syncthreads();
  {
    int h = tid;
    float sr = 0, si = 0;
    for (int ky = 0; ky < 128; ++ky) {
      int t = (h*ky) & 127;
      float ar = ewr[ky], ai = ewi[ky];
      sr += ar*twr[t] + ai*twi[t];
      si += ai*twr[t] - ar*twi[t];
    }
    float* o = ws + OFF_VR + ((n*HH + h)*KXN + kx)*2;
    o[0] = sr; o[1] = si;
  }
}

__global__ __launch_bounds__(256) void k_ifft_rows(float* __restrict__ ws) {
  __shared__ float twr[128], twi[128];
  int tid = threadIdx.x;
  if (tid < 128) { float s, c; sincosf(-2.0f*PI_F*(float)tid/128.0f, &s, &c); twr[tid]=c; twi[tid]=s; }
  __syncthreads();
  int idx = blockIdx.x*256 + tid, n = blockIdx.y;
  int h = idx >> 7, w = idx & 127;
  const float* Vr = ws + OFF_VR + (size_t)n*HH*KXN*2;
  float s = 0.0f;
  for (int kx = 0; kx <= 64; ++kx) {
    int t = (w*kx) & 127;
    float ar = Vr[(h*KXN + kx)*2], ai = Vr[(h*KXN + kx)*2 + 1];
    float re = ar*twr[t] + ai*twi[t];
    s += (kx == 0 || kx == 64) ? re : 2.0f*re;
  }
  ws[OFF_WB + (n*HH + h)*WW + w] = s * (1.0f/16384.0f);
}

// ---------------------------------------------------------------------------
// k_xnew v2: slab+slide correlate-back (verified round 9).
// ---------------------------------------------------------------------------
__global__ __launch_bounds__(256) void k_xnew(const float* __restrict__ x,
                                              const float* __restrict__ dict,
                                              const float* __restrict__ ws,
                                              float* __restrict__ out) {
  __shared__ __align__(16) float xs[68*SD];
  __shared__ float psf_s[25];
  int c = blockIdx.x, n = blockIdx.y, hh = blockIdx.z;
  int tid = threadIdx.x;
  if (tid < 25) psf_s[tid] = dict[(n*CIN + c)*25 + 24 - tid];   // flipped kernel
  const float* Wb = ws + OFF_WB + (size_t)n*NPIX;
  int rbase = hh*64 - 2;
  for (int k = tid; k < 68*132; k += 256) {
    int R = k / 132, C = k - R*132;
    int gh = (rbase + R) & 127;
    int gw = (C - 2) & 127;
    xs[R*SD + C] = Wb[gh*128 + gw];
  }
  __syncthreads();
  int cs = tid & 31, rs = tid >> 5;
  int c0 = cs*4, r0 = rs*8;
  float w[5][8];
#pragma unroll
  for (int k = 0; k < 4; ++k) {
    f32x4 a = *(const f32x4*)&xs[(r0+k)*SD + c0];
    f32x4 b = *(const f32x4*)&xs[(r0+k)*SD + c0 + 4];
#pragma unroll
    for (int e = 0; e < 4; ++e) { w[k][e] = a[e]; w[k][4+e] = b[e]; }
  }
  const float* Xc = x   + (size_t)(n*CIN + c)*NPIX + (size_t)(hh*64 + r0)*128 + c0;
  float*       Oc = out + (size_t)(n*CIN + c)*NPIX + (size_t)(hh*64 + r0)*128 + c0;
#pragma unroll
  for (int row = 0; row < 8; ++row) {
    int slot = (row + 4) % 5;
    f32x4 a = *(const f32x4*)&xs[(r0+row+4)*SD + c0];
    f32x4 b = *(const f32x4*)&xs[(r0+row+4)*SD + c0 + 4];
#pragma unroll
    for (int e = 0; e < 4; ++e) { w[slot][e] = a[e]; w[slot][4+e] = b[e]; }
    f32x4 acc = *(const f32x4*)(Xc + (size_t)row*128);
#pragma unroll
    for (int u = 0; u < 5; ++u)
#pragma unroll
      for (int v = 0; v < 5; ++v) {
        float pv = psf_s[u*5 + v];
#pragma unroll
        for (int p = 0; p < 4; ++p)
          acc[p] += pv * w[(row+u) % 5][p+v];
      }
    *(f32x4*)(Oc + (size_t)row*128) = acc;
  }
}

// ---------------------------------------------------------------------------
// k_pad: x_new -> zero-padded bf16 image, two copies (copy1 offset by one
// element so odd-v shifted reads are dword-aligned).
// ---------------------------------------------------------------------------
__global__ __launch_bounds__(256) void k_pad(const float* __restrict__ xn,
                                             float* __restrict__ ws) {
  ushort* xb0 = (ushort*)(ws + OFF_XB);
  ushort* xb1 = xb0 + XB0C;
  int ch = blockIdx.y;
  int idx = blockIdx.x*256 + threadIdx.x;
  if (ch == 0 && idx == 0) xb1[0] = 0;
  if (idx >= 136*136) return;
  int hp = idx / 136, wp = idx % 136;
  float v = 0.0f;
  if (hp >= 4 && hp < 132 && wp >= 4 && wp < 132)
    v = xn[(size_t)ch*NPIX + (hp-4)*128 + (wp-4)];
  __hip_bfloat16 b = __float2bfloat16(v);
  ushort bits = *(ushort*)&b;
  size_t o = (size_t)ch*18496 + idx;
  xb0[o] = bits;
  xb1[o + 1] = bits;
}

// ---------------------------------------------------------------------------
// k_gemm v8 (verified 44-46us; v9 dbuf and v10 32x32 both regressed).
// Bound by barrier-synchronized staging latency; staging decode
// (4 rows x 256B contiguous per instr) is the critical property.
// ---------------------------------------------------------------------------
__global__ __launch_bounds__(256, 3) void k_gemm(float* __restrict__ ws) {
  __shared__ __align__(16) ushort sA0[64*128];
  __shared__ __align__(16) ushort sA1[64*128];
  __shared__ __align__(16) ushort sB [64*128];

  const ushort* xb0 = (const ushort*)(ws + OFF_XB);
  const ushort* xb1 = xb0 + XB0C;
  int fid = blockIdx.x;
  int xcd = fid & 7, l = fid >> 3;        // l in [0,84)
  int nn = xcd & 3, hi = xcd >> 2;        // 2 XCDs per n; hi = sl parity
  int g = l % 21, m = l / 21;             // m in [0,4)
  int sl = m*2 + hi;                      // [0,8), K-slice of 2048

  int tid = threadIdx.x;
  int wv = tid >> 6, lane = tid & 63;
  int l16 = lane & 15, quad = lane >> 4;
  int lr = lane >> 4, lc = lane & 15;     // stage decode (4 rows x 16 cols)

  // shifts handled by this block
  int sidx0 = 2*g;
  int sidx1 = 2*g + 1;
  int sval1 = (sidx1 <= 40);
  if (sidx1 > 40) sidx1 = 40;
  int uv0 = sidx0 + 40, uv1 = sidx1 + 40;
  int u0 = uv0 / 9, v0 = uv0 % 9;
  int u1 = uv1 / 9, v1 = uv1 % 9;

  size_t chanBase = (size_t)(nn*64) * 18496;
  int ridx0 = sl * 16;                     // first image row of this K-slice
  // per-row-start pointers (element units), advanced by 136 per round
  const ushort* pB  = xb0 + chanBase + 548 + (size_t)ridx0*136;   // row 4, col 4
  size_t a0e = chanBase + (size_t)(u0 + ridx0)*136 + v0;
  size_t a1e = chanBase + (size_t)(u1 + ridx0)*136 + v1;
  const ushort* pA0 = (v0 & 1) ? (xb1 + a0e + 1) : (xb0 + a0e);
  const ushort* pA1 = (v1 & 1) ? (xb1 + a1e + 1) : (xb0 + a1e);

  f32x4 acc[2][4];
#pragma unroll
  for (int s = 0; s < 2; ++s)
#pragma unroll
    for (int jt = 0; jt < 4; ++jt) acc[s][jt] = (f32x4){0.f,0.f,0.f,0.f};

  for (int r = 0; r < 16; ++r) {
    if (r) __syncthreads();
    // ---- stage 3 tiles: wave wv covers rows wv*16 .. wv*16+15 ----
#pragma unroll
    for (int c = 0; c < 4; ++c) {
      int row = wv*16 + c*4 + lr;
      int sw = ((lc ^ (row & 15)) * 8);
      size_t goff = (size_t)row * 18496 + (size_t)lc * 8;
      {  // B: 8B-aligned source -> two uint2 loads
        const uint2* p = (const uint2*)(pB + goff);
        uint2 b0 = p[0], b1 = p[1];
        *(uint2*)&sB[row*128 + sw]     = b0;
        *(uint2*)&sB[row*128 + sw + 4] = b1;
      }
      {  // A0: 4B-aligned source -> four dword loads
        const uint* p = (const uint*)(pA0 + goff);
        uint4 v4; v4.x = p[0]; v4.y = p[1]; v4.z = p[2]; v4.w = p[3];
        *(uint4*)&sA0[row*128 + sw] = v4;
      }
      {  // A1
        const uint* p = (const uint*)(pA1 + goff);
        uint4 v4; v4.x = p[0]; v4.y = p[1]; v4.z = p[2]; v4.w = p[3];
        *(uint4*)&sA1[row*128 + sw] = v4;
      }
    }
    __syncthreads();
    // ---- compute 4 kt (K=32 each) ----
#pragma unroll
    for (int kt = 0; kt < 4; ++kt) {
      int c16 = kt*4 + quad;
      int sw = ((c16 ^ l16) * 8);
      bf16x8 af0 = *(const bf16x8*)&sA0[(wv*16 + l16)*128 + sw];
      bf16x8 af1 = *(const bf16x8*)&sA1[(wv*16 + l16)*128 + sw];
      bf16x8 bf[4];
#pragma unroll
      for (int jt = 0; jt < 4; ++jt)
        bf[jt] = *(const bf16x8*)&sB[(jt*16 + l16)*128 + sw];
#pragma unroll
      for (int jt = 0; jt < 4; ++jt) {
        acc[0][jt] = __builtin_amdgcn_mfma_f32_16x16x32_bf16(af0, bf[jt], acc[0][jt], 0, 0, 0);
        acc[1][jt] = __builtin_amdgcn_mfma_f32_16x16x32_bf16(af1, bf[jt], acc[1][jt], 0, 0, 0);
      }
    }
    pB += 136; pA0 += 136; pA1 += 136;
  }

  // ---- epilogue: plain vector stores into slice-private staging ----
  int io = wv*16 + quad*4;
  {
    float* dst = ws + OFF_RP + (((size_t)nn*8 + sl)*41 + sidx0)*4096;
#pragma unroll
    for (int jt = 0; jt < 4; ++jt) {
      int jout = jt*16 + l16;
      *reinterpret_cast<f32x4*>(dst + jout*64 + io) = acc[0][jt];
    }
  }
  if (sval1) {
    float* dst = ws + OFF_RP + (((size_t)nn*8 + sl)*41 + sidx1)*4096;
#pragma unroll
    for (int jt = 0; jt < 4; ++jt) {
      int jout = jt*16 + l16;
      *reinterpret_cast<f32x4*>(dst + jout*64 + io) = acc[1][jt];
    }
  }
}

// ---------------------------------------------------------------------------
// k_rsumtrans: per (n,s) plane, sum 8 K-slices (coalesced) -> P (slot 0)
// and 64x64 transpose -> PT (slot 1). Verified round 7.
// ---------------------------------------------------------------------------
__global__ __launch_bounds__(256) void k_rsumtrans(float* __restrict__ ws) {
  __shared__ float tile[64][65];
  int s = blockIdx.x, n = blockIdx.y;
  float* base0 = ws + OFF_RP + ((size_t)n*8)*SLAB + (size_t)s*4096;
  int t = threadIdx.x;
#pragma unroll
  for (int p = 0; p < 4; ++p) {
    int vidx = p*256 + t;                 // 0..1023, 16 f32x4 per row
    int row = vidx >> 4, c0 = (vidx & 15)*4;
    f32x4 sum = (f32x4){0.f,0.f,0.f,0.f};
#pragma unroll
    for (int sl = 0; sl < 8; ++sl)
      sum += *(const f32x4*)(base0 + (size_t)sl*SLAB + row*64 + c0);
    *(f32x4*)(base0 + row*64 + c0) = sum;           // P, slot 0
    tile[row][c0]   = sum[0]; tile[row][c0+1] = sum[1];
    tile[row][c0+2] = sum[2]; tile[row][c0+3] = sum[3];
  }
  __syncthreads();
  float* PT = base0 + SLAB;                          // slot 1
#pragma unroll
  for (int p = 0; p < 4; ++p) {
    int vidx = p*256 + t;
    int row = vidx >> 4, c0 = (vidx & 15)*4;
    f32x4 o;
#pragma unroll
    for (int e = 0; e < 4; ++e) o[e] = tile[c0+e][row];
    *(f32x4*)(PT + row*64 + c0) = o;
  }
}

// ---------------------------------------------------------------------------
// k_rmerge v4: R relaid as [n][j][uv][i] so CG's per-lane-i reads are
// coalesced. Verified round 8.
// ---------------------------------------------------------------------------
__global__ __launch_bounds__(256) void k_rmerge(float* __restrict__ ws) {
  int j = blockIdx.x, n = blockIdx.y;
  const float* P  = ws + OFF_RP + ((size_t)n*8 + 0)*SLAB;
  const float* PT = ws + OFF_RP + ((size_t)n*8 + 1)*SLAB;
  float* out = ws + OFF_R + ((size_t)(n*64 + j))*81*64;
  int t = threadIdx.x;
  for (int k = t; k < 81*64; k += 256) {
    int uv = k >> 6, i = k & 63;
    float v = (uv >= 40) ? P [(size_t)(uv-40)*4096 + j*64 + i]
                         : PT[(size_t)(40-uv)*4096 + j*64 + i];
    out[k] = v;
  }
}

// ---------------------------------------------------------------------------
// k_pm v3: slab-staged sliding-window XtY (verified round 6: off the top-5).
// ---------------------------------------------------------------------------
__global__ __launch_bounds__(256) void k_pm(const float* __restrict__ xn,
                                            const float* __restrict__ y,
                                            float* __restrict__ ws) {
  __shared__ __align__(16) float xs[68*SD];
  __shared__ float red_s[4][25];
  int i = blockIdx.x, n = blockIdx.y, hh = blockIdx.z;
  int tid = threadIdx.x;
  const float* Xi = xn + (size_t)(n*CIN + i)*NPIX;
  int rbase = hh*64 - 2;
  for (int k = tid; k < 68*132; k += 256) {
    int R = k / 132, C = k - R*132;
    int hr = rbase + R, wc = C - 2;
    float v = 0.0f;
    if (hr >= 0 && hr < 128 && wc >= 0 && wc < 128) v = Xi[hr*128 + wc];
    xs[R*SD + C] = v;
  }
  __syncthreads();
  int cs = tid & 31, rs = tid >> 5;
  int c0 = cs*4, r0 = rs*8;
  float w[5][8];
#pragma unroll
  for (int k = 0; k < 4; ++k) {
    f32x4 a = *(const f32x4*)&xs[(r0+k)*SD + c0];
    f32x4 b = *(const f32x4*)&xs[(r0+k)*SD + c0 + 4];
#pragma unroll
    for (int e = 0; e < 4; ++e) { w[k][e] = a[e]; w[k][4+e] = b[e]; }
  }
  float acc[25];
#pragma unroll
  for (int t = 0; t < 25; ++t) acc[t] = 0.0f;
  const float* yp = y + (size_t)n*NPIX + (size_t)(hh*64 + r0)*128 + c0;
#pragma unroll
  for (int row = 0; row < 8; ++row) {
    int slot = (row + 4) % 5;
    f32x4 a = *(const f32x4*)&xs[(r0+row+4)*SD + c0];
    f32x4 b = *(const f32x4*)&xs[(r0+row+4)*SD + c0 + 4];
#pragma unroll
    for (int e = 0; e < 4; ++e) { w[slot][e] = a[e]; w[slot][4+e] = b[e]; }
    f32x4 yv = *(const f32x4*)(yp + (size_t)row*128);
#pragma unroll
    for (int u = 0; u < 5; ++u)
#pragma unroll
      for (int v = 0; v < 5; ++v) {
#pragma unroll
        for (int p = 0; p < 4; ++p)
          acc[u*5+v] += w[(row+u) % 5][p+v] * yv[p];
      }
  }
  int lane = tid & 63, wv = tid >> 6;
#pragma unroll
  for (int t = 0; t < 25; ++t) {
    float v = acc[t];
    WRED(v);
    if (lane == 0) red_s[wv][t] = v;
  }
  __syncthreads();
  if (tid < 25) {
    float s = red_s[0][tid] + red_s[1][tid] + red_s[2][tid] + red_s[3][tid];
    ws[OFF_PP + ((size_t)(hh*4 + n)*64 + i)*25 + tid] = s;
  }
}

__global__ __launch_bounds__(64) void k_pm2(const float* __restrict__ dict,
                                            const float* __restrict__ alpha_d,
                                            const float* __restrict__ regp,
                                            float* __restrict__ ws) {
  int i = blockIdx.x, n = blockIdx.y, t = threadIdx.x;
  if (t >= 25) return;
  float s = 0.0f;
#pragma unroll
  for (int tg = 0; tg < 2; ++tg) s += ws[OFF_PP + ((size_t)(tg*4 + n)*64 + i)*25 + t];
  float ad = alpha_d[n] * 16384.0f * regp[0] * (1.0f/1600.0f);
  float val = s + ad * dict[(n*CIN + i)*25 + t];
  int idx = n*MMAT + i*25 + t;
  ws[OFF_RV + idx] = val;
  ws[OFF_PV + idx] = val;
}

// ---------------------------------------------------------------------------
// CG: k_cg_first computes Ap0 + pAp0 partials (per j, no atomics).
// R layout [n][j][uv][i]: lane i reads Rj[uv*64+i] -> coalesced.
// ---------------------------------------------------------------------------
__global__ __launch_bounds__(256) void k_cg_first(float* __restrict__ ws,
                                                  const float* __restrict__ alpha_d,
                                                  const float* __restrict__ regp) {
  __shared__ float vv[MMAT];
  __shared__ float part[25][66];
  int n = blockIdx.y, j = blockIdx.x, tid = threadIdx.x;
  for (int t = tid; t < MMAT; t += 256) vv[t] = ws[OFF_PV + n*MMAT + t];
  __syncthreads();
  int i = tid & 63, qq = tid >> 6;
  const float* Rj = ws + OFF_R + ((size_t)(n*CIN + j))*81*64;
  const float* vi = &vv[i*25];
#pragma unroll
  for (int s6 = 0; s6 < 7; ++s6) {
    int ac = qq + 4*s6;
    if (ac < 25) {
      int a = ac/5, c = ac%5;
      float s = 0.0f;
#pragma unroll
      for (int b = 0; b < 5; ++b)
#pragma unroll
        for (int d = 0; d < 5; ++d)
          s += Rj[((4+b-a)*9 + (4+d-c))*64 + i] * vi[b*5+d];
      part[ac][i] = s;
    }
  }
  __syncthreads();
  float contrib = 0.0f;
  if (tid < 25) {
    float s = 0.0f;
    for (int t = 0; t < 64; ++t) s += part[tid][t];
    float reg = alpha_d[n] * 16384.0f * regp[0] * (1.0f/1600.0f);
    s += reg * vv[j*25 + tid];
    ws[OFF_AP + n*MMAT + j*25 + tid] = s;
    contrib = s * vv[j*25 + tid];
  }
  if (tid < 64) {
    WRED(contrib);
    if (tid == 0) ws[OFF_PAPP + 0*256 + n*64 + j] = contrib;
  }
}

// ---------------------------------------------------------------------------
// Fused CG step: full r in LDS; rr/alpha/beta in-block (identical across
// blocks); matvec A r_new; updates 25-elem segments; pAp partial per j.
// RV double-buffered by iteration parity -> race-free across blocks.
// ---------------------------------------------------------------------------
__global__ __launch_bounds__(256) void k_cg_step(float* __restrict__ ws, int it,
                                                 int last, float* __restrict__ out,
                                                 const float* __restrict__ alpha_d,
                                                 const float* __restrict__ regp) {
  __shared__ float vv[MMAT];       // r_new
  __shared__ float red_s[9];
  __shared__ float part[25][66];
  int n = blockIdx.y, j = blockIdx.x, tid = threadIdx.x;
  const float* rsrc = ws + ((it & 1) ? OFF_RV2 : OFF_RV) + n*MMAT;
  float*       rdst = ws + ((it & 1) ? OFF_RV  : OFF_RV2) + n*MMAT;
  int lane = tid & 63, wvi = tid >> 6;

  float rold[7], apv[7];
  float rrp = 0.0f;
#pragma unroll
  for (int t = 0; t < 7; ++t) {
    int idx = tid + 256*t;
    rold[t] = 0.0f; apv[t] = 0.0f;
    if (idx < MMAT) {
      rold[t] = rsrc[idx];
      apv[t]  = ws[OFF_AP + n*MMAT + idx];
      rrp += rold[t]*rold[t];
    }
  }
  WRED(rrp);
  if (lane == 0) red_s[wvi] = rrp;
  float pp = (tid < 64) ? ws[OFF_PAPP + it*256 + n*64 + tid] : 0.0f;
  if (tid < 64) { WRED(pp); if (tid == 0) red_s[4] = pp; }
  __syncthreads();
  float rr_old = red_s[0] + red_s[1] + red_s[2] + red_s[3];
  float alpha = rr_old / (red_s[4] + 1e-30f);

  if (last) {
    if (tid < 25) {
      int idx = n*MMAT + j*25 + tid;
      float dv = ws[OFF_DV + idx] + alpha * ws[OFF_PV + idx];
      out[4194304 + n*MMAT + j*25 + tid] = dv;
    }
    return;
  }

  float rrnp = 0.0f;
#pragma unroll
  for (int t = 0; t < 7; ++t) {
    int idx = tid + 256*t;
    if (idx < MMAT) {
      float rn = rold[t] - alpha * apv[t];
      vv[idx] = rn;
      rrnp += rn*rn;
    }
  }
  WRED(rrnp);
  __syncthreads();                           // vv complete
  if (lane == 0) red_s[5 + wvi] = rrnp;
  __syncthreads();
  float rr_new = red_s[5] + red_s[6] + red_s[7] + red_s[8];
  float beta = rr_new / (rr_old + 1e-30f);

  int i = tid & 63, qq = tid >> 6;
  const float* Rj = ws + OFF_R + ((size_t)(n*CIN + j))*81*64;
  const float* vi = &vv[i*25];
#pragma unroll
  for (int s6 = 0; s6 < 7; ++s6) {
    int ac = qq + 4*s6;
    if (ac < 25) {
      int a = ac/5, c = ac%5;
      float s = 0.0f;
#pragma unroll
      for (int b = 0; b < 5; ++b)
#pragma unroll
        for (int d = 0; d < 5; ++d)
          s += Rj[((4+b-a)*9 + (4+d-c))*64 + i] * vi[b*5+d];
      part[ac][i] = s;
    }
  }
  __syncthreads();
  float contrib = 0.0f;
  if (tid < 25) {
    float s = 0.0f;
    for (int t = 0; t < 64; ++t) s += part[tid][t];
    float reg = alpha_d[n] * 16384.0f * regp[0] * (1.0f/1600.0f);
    float rn_seg = vv[j*25 + tid];
    s += reg * rn_seg;
    int idx = n*MMAT + j*25 + tid;
    float p_old = ws[OFF_PV + idx];
    float dv = ws[OFF_DV + idx] + alpha * p_old;
    float pn  = rn_seg + beta * p_old;
    float apn = s + beta * ws[OFF_AP + idx];
    ws[OFF_DV + idx] = dv;
    ws[OFF_PV + idx] = pn;
    ws[OFF_AP + idx] = apn;
    rdst[j*25 + tid] = rn_seg;
    contrib = pn * apn;
  }
  if (tid < 64) {
    WRED(contrib);
    if (tid == 0) ws[OFF_PAPP + (it+1)*256 + n*64 + j] = contrib;
  }
}

// ---------------------------------------------------------------------------
extern "C" void kernel_launch(void* const* d_in, const int* in_sizes, int n_in,
                              void* d_out, int out_size, void* d_ws, size_t ws_size,
                              hipStream_t stream) {
  (void)in_sizes; (void)n_in; (void)out_size; (void)ws_size;
  const float* x    = (const float*)d_in[0];
  const float* dict = (const float*)d_in[1];
  const float* y    = (const float*)d_in[2];
  const float* ax   = (const float*)d_in[3];
  const float* ad   = (const float*)d_in[4];
  const float* regp = (const float*)d_in[5];
  float* out = (float*)d_out;
  float* ws  = (float*)d_ws;

  dim3 b256(256);
  k_sinv<<<dim3(33,4), b256, 0, stream>>>(dict, ax, ws);
  k_e<<<dim3(64,4,2), b256, 0, stream>>>(x, dict, ws);
  k_e2<<<dim3(64,4), b256, 0, stream>>>(y, ws);
  k_fft_rows<<<dim3(33,4), b256, 0, stream>>>(ws);
  k_fft_colpipe<<<dim3(65,4), dim3(128), 0, stream>>>(ws);
  k_ifft_rows<<<dim3(64,4), b256, 0, stream>>>(ws);
  k_xnew<<<dim3(64,4,2), b256, 0, stream>>>(x, dict, ws, out);

  // ---- R via MFMA: pad, LDS-staged shift-GEMM, slice-sum+transpose, merge
  k_pad<<<dim3(73,256), b256, 0, stream>>>(out, ws);
  k_gemm<<<dim3(672), b256, 0, stream>>>(ws);
  k_rsumtrans<<<dim3(41,4), b256, 0, stream>>>(ws);
  k_rmerge<<<dim3(64,4), b256, 0, stream>>>(ws);

  k_pm<<<dim3(64,4,2), b256, 0, stream>>>(out, y, ws);
  k_pm2<<<dim3(64,4), dim3(64), 0, stream>>>(dict, ad, regp, ws);

  // ---- CG (fused steps; NIT+1 launches) ----
  k_cg_first<<<dim3(64,4), b256, 0, stream>>>(ws, ad, regp);
  for (int it = 0; it < NIT; ++it)
    k_cg_step<<<dim3(64,4), b256, 0, stream>>>(ws, it, (it == NIT-1) ? 1 : 0, out, ad, regp);
}

// Round 15
// 255.636 us; speedup vs baseline: 1.7464x; 1.0421x over previous
//
#include <hip/hip_runtime.h>
#include <hip/hip_bf16.h>
#include <math.h>

#define PI_F 3.14159265358979323846f

#define NS   4
#define CIN  64
#define HH   128
#define WW   128
#define KXN  65          // rfft last-axis size
#define NPIX (HH*WW)
#define MMAT 1600        // CIN*5*5
#define NIT  5           // CG iterations (verified round 12: absmax 0.0378 < 0.0988)
#define SD   136         // LDS halo row stride (16B-aligned)
#define SLAB 167936      // 41*4096 floats, one (n,sl) staging slab

// float offsets in workspace (budget: 11,937,536 floats = 47.75 MB, proven)
#define OFF_SINV 0
#define OFF_E    33280
#define OFF_ER   98816
#define OFF_VR   231936
#define OFF_WB   298496
#define OFF_R    364032      // 4*64*81*64 = 1,327,104 floats -> ends 1,691,136 (layout [n][j][uv][i])
#define OFF_RP   1691136    // Rst2: 4 n * 8 sl * 41 s * 4096 = 5,373,952 floats -> ends 7,065,088
#define OFF_EP   1691136    // k_e partials: 64 c * 4 n * 16384 (dead before k_gemm)
#define OFF_PP   1691136    // k_pm partials: 2 hh * 4 n * 64 i * 25 (written after rsumtrans reads slabs)
#define OFF_XB   7196160    // bf16 padded copies: 2*4,734,976 ushorts + guard
#define XB0C     4734976    // ushorts per copy (4*64*136*136)
// CG state reuses the (dead-by-then) front-end scratch at offset 0:
#define OFF_DV   0
#define OFF_RV   6400
#define OFF_PV   12800
#define OFF_AP   19200
#define OFF_RV2  25600      // double-buffer for r (iteration parity)
#define OFF_PAPP 32000      // [it*256 + n*64 + j] pAp partials

#define WRED(x) { (x)+=__shfl_down((x),32); (x)+=__shfl_down((x),16); (x)+=__shfl_down((x),8); \
                  (x)+=__shfl_down((x),4);  (x)+=__shfl_down((x),2);  (x)+=__shfl_down((x),1); }

typedef __attribute__((ext_vector_type(8))) short bf16x8;
typedef __attribute__((ext_vector_type(4))) float f32x4;

// ---------------------------------------------------------------------------
// k_sinv v2: per-block 128-entry twiddle table; (ky*(a-2)) & 127 indexing.
// ---------------------------------------------------------------------------
__global__ __launch_bounds__(256) void k_sinv(const float* __restrict__ dict,
                                              const float* __restrict__ alpha_x,
                                              float* __restrict__ ws) {
  __shared__ float twr[128], twi[128];
  int tid = threadIdx.x;
  if (tid < 128) { float s, c; sincosf(-2.0f*PI_F*(float)tid/128.0f, &s, &c); twr[tid]=c; twi[tid]=s; }
  __syncthreads();
  int idx = blockIdx.x * 256 + tid;
  int n = blockIdx.y;
  if (idx >= HH * KXN) return;
  int ky = idx / KXN, kx = idx % KXN;
  float tr[25], ti[25];
  {
    float eyr[5], eyi[5], exr[5], exi[5];
#pragma unroll
    for (int a = 0; a < 5; ++a) {
      int my = (ky * (a - 2)) & 127;
      eyr[a] = twr[my]; eyi[a] = twi[my];
      int mx = (kx * (a - 2)) & 127;
      exr[a] = twr[mx]; exi[a] = twi[mx];
    }
#pragma unroll
    for (int a = 0; a < 5; ++a)
#pragma unroll
      for (int b = 0; b < 5; ++b) {
        tr[a*5+b] = eyr[a]*exr[b] - eyi[a]*exi[b];
        ti[a*5+b] = eyr[a]*exi[b] + eyi[a]*exr[b];
      }
  }
  const float* dn = dict + n * CIN * 25;
  float S = 0.0f;
  for (int c = 0; c < CIN; ++c) {
    const float* p = dn + c * 25;
    float Dr = 0.0f, Di = 0.0f;
#pragma unroll
    for (int t = 0; t < 25; ++t) { Dr += p[t]*tr[t]; Di += p[t]*ti[t]; }
    S += Dr*Dr + Di*Di;
  }
  float a = alpha_x[n] * (1.0f/64.0f);
  ws[OFF_SINV + (n*HH + ky)*KXN + kx] = 1.0f / (S + a);
}

// ---------------------------------------------------------------------------
// k_e v3: one block = one (channel, n, half-image); slab staged once, then
// pure LDS/VALU sliding-window conv (verified round 6).
// ---------------------------------------------------------------------------
__global__ __launch_bounds__(256) void k_e(const float* __restrict__ x,
                                           const float* __restrict__ dict,
                                           float* __restrict__ ws) {
  __shared__ __align__(16) float xs[68*SD];
  __shared__ float psf_s[25];
  int c = blockIdx.x, n = blockIdx.y, hh = blockIdx.z;
  int tid = threadIdx.x;
  if (tid < 25) psf_s[tid] = dict[(n*CIN + c)*25 + tid];
  const float* Xc = x + (size_t)(n*CIN + c)*NPIX;
  int rbase = hh*64 - 2;
  for (int k = tid; k < 68*132; k += 256) {
    int R = k / 132, C = k - R*132;
    int gh = (rbase + R) & 127;
    int gw = (C - 2) & 127;
    xs[R*SD + C] = Xc[gh*128 + gw];
  }
  __syncthreads();
  int cs = tid & 31, rs = tid >> 5;
  int c0 = cs*4, r0 = rs*8;            // output cols c0..c0+3, rows r0..r0+7
  float w[5][8];
#pragma unroll
  for (int k = 0; k < 4; ++k) {
    f32x4 a = *(const f32x4*)&xs[(r0+k)*SD + c0];
    f32x4 b = *(const f32x4*)&xs[(r0+k)*SD + c0 + 4];
#pragma unroll
    for (int e = 0; e < 4; ++e) { w[k][e] = a[e]; w[k][4+e] = b[e]; }
  }
  float* EPo = ws + OFF_EP + (size_t)(c*4 + n)*NPIX + (size_t)(hh*64 + r0)*128 + c0;
#pragma unroll
  for (int row = 0; row < 8; ++row) {
    int slot = (row + 4) % 5;
    f32x4 a = *(const f32x4*)&xs[(r0+row+4)*SD + c0];
    f32x4 b = *(const f32x4*)&xs[(r0+row+4)*SD + c0 + 4];
#pragma unroll
    for (int e = 0; e < 4; ++e) { w[slot][e] = a[e]; w[slot][4+e] = b[e]; }
    f32x4 acc = (f32x4){0.f,0.f,0.f,0.f};
#pragma unroll
    for (int u = 0; u < 5; ++u)
#pragma unroll
      for (int v = 0; v < 5; ++v) {
        float pv = psf_s[u*5 + v];
#pragma unroll
        for (int p = 0; p < 4; ++p)
          acc[p] += pv * w[(row+u) % 5][p+v];
      }
    *(f32x4*)(EPo + (size_t)row*128) = acc;
  }
}

__global__ __launch_bounds__(256) void k_e2(const float* __restrict__ y,
                                            float* __restrict__ ws) {
  int n = blockIdx.y;
  int p = blockIdx.x*256 + threadIdx.x;     // grid.x = 64 -> covers 16384
  float s = 0.0f;
#pragma unroll 8
  for (int c = 0; c < CIN; ++c) s += ws[OFF_EP + (size_t)(c*4 + n)*NPIX + p];
  ws[OFF_E + n*NPIX + p] = y[n*NPIX + p] - s;
}

// ---------------------------------------------------------------------------
// row DFT
// ---------------------------------------------------------------------------
__global__ __launch_bounds__(256) void k_fft_rows(float* __restrict__ ws) {
  __shared__ float twr[128], twi[128];
  int tid = threadIdx.x;
  if (tid < 128) { float s, c; sincosf(-2.0f*PI_F*(float)tid/128.0f, &s, &c); twr[tid]=c; twi[tid]=s; }
  __syncthreads();
  int idx = blockIdx.x*256 + tid, n = blockIdx.y;
  if (idx >= HH*KXN) return;
  int h = idx / KXN, k = idx % KXN;
  const float* row = ws + OFF_E + (n*HH + h)*WW;
  float sr = 0, si = 0;
  for (int w = 0; w < 128; ++w) {
    int t = (w*k) & 127;
    float v = row[w];
    sr += v*twr[t]; si += v*twi[t];
  }
  float* o = ws + OFF_ER + ((n*HH + h)*KXN + k)*2;
  o[0] = sr; o[1] = si;
}

// ---------------------------------------------------------------------------
// column pipeline: fwd DFT * Sinv, inverse DFT — column stays in LDS
// ---------------------------------------------------------------------------
__global__ __launch_bounds__(128) void k_fft_colpipe(float* __restrict__ ws) {
  __shared__ float twr[128], twi[128];
  __shared__ float ecr[128], eci[128];
  __shared__ float ewr[128], ewi[128];
  int tid = threadIdx.x;
  int kx = blockIdx.x, n = blockIdx.y;
  { float s, c; sincosf(-2.0f*PI_F*(float)tid/128.0f, &s, &c); twr[tid]=c; twi[tid]=s; }
  const float* Er = ws + OFF_ER + (size_t)n*HH*KXN*2;
  ecr[tid] = Er[(tid*KXN + kx)*2];
  eci[tid] = Er[(tid*KXN + kx)*2 + 1];
  __syncthreads();
  {
    int ky = tid;
    float sr = 0, si = 0;
    for (int h = 0; h < 128; ++h) {
      int t = (h*ky) & 127;
      float ar = ecr[h], ai = eci[h];
      sr += ar*twr[t] - ai*twi[t];
      si += ar*twi[t] + ai*twr[t];
    }
    float sv = ws[OFF_SINV + (n*HH + ky)*KXN + kx];
    ewr[ky] = sr*sv; ewi[ky] = si*sv;
  }
  __syncthreads();
  {
    int h = tid;
    float sr = 0, si = 0;
    for (int ky = 0; ky < 128; ++ky) {
      int t = (h*ky) & 127;
      float ar = ewr[ky], ai = ewi[ky];
      sr += ar*twr[t] + ai*twi[t];
      si += ai*twr[t] - ar*twi[t];
    }
    float* o = ws + OFF_VR + ((n*HH + h)*KXN + kx)*2;
    o[0] = sr; o[1] = si;
  }
}

__global__ __launch_bounds__(256) void k_ifft_rows(float* __restrict__ ws) {
  __shared__ float twr[128], twi[128];
  int tid = threadIdx.x;
  if (tid < 128) { float s, c; sincosf(-2.0f*PI_F*(float)tid/128.0f, &s, &c); twr[tid]=c; twi[tid]=s; }
  __syncthreads();
  int idx = blockIdx.x*256 + tid, n = blockIdx.y;
  int h = idx >> 7, w = idx & 127;
  const float* Vr = ws + OFF_VR + (size_t)n*HH*KXN*2;
  float s = 0.0f;
  for (int kx = 0; kx <= 64; ++kx) {
    int t = (w*kx) & 127;
    float ar = Vr[(h*KXN + kx)*2], ai = Vr[(h*KXN + kx)*2 + 1];
    float re = ar*twr[t] + ai*twi[t];
    s += (kx == 0 || kx == 64) ? re : 2.0f*re;
  }
  ws[OFF_WB + (n*HH + h)*WW + w] = s * (1.0f/16384.0f);
}

// ---------------------------------------------------------------------------
// k_xnew v2: slab+slide correlate-back (verified round 9).
// ---------------------------------------------------------------------------
__global__ __launch_bounds__(256) void k_xnew(const float* __restrict__ x,
                                              const float* __restrict__ dict,
                                              const float* __restrict__ ws,
                                              float* __restrict__ out) {
  __shared__ __align__(16) float xs[68*SD];
  __shared__ float psf_s[25];
  int c = blockIdx.x, n = blockIdx.y, hh = blockIdx.z;
  int tid = threadIdx.x;
  if (tid < 25) psf_s[tid] = dict[(n*CIN + c)*25 + 24 - tid];   // flipped kernel
  const float* Wb = ws + OFF_WB + (size_t)n*NPIX;
  int rbase = hh*64 - 2;
  for (int k = tid; k < 68*132; k += 256) {
    int R = k / 132, C = k - R*132;
    int gh = (rbase + R) & 127;
    int gw = (C - 2) & 127;
    xs[R*SD + C] = Wb[gh*128 + gw];
  }
  __syncthreads();
  int cs = tid & 31, rs = tid >> 5;
  int c0 = cs*4, r0 = rs*8;
  float w[5][8];
#pragma unroll
  for (int k = 0; k < 4; ++k) {
    f32x4 a = *(const f32x4*)&xs[(r0+k)*SD + c0];
    f32x4 b = *(const f32x4*)&xs[(r0+k)*SD + c0 + 4];
#pragma unroll
    for (int e = 0; e < 4; ++e) { w[k][e] = a[e]; w[k][4+e] = b[e]; }
  }
  const float* Xc = x   + (size_t)(n*CIN + c)*NPIX + (size_t)(hh*64 + r0)*128 + c0;
  float*       Oc = out + (size_t)(n*CIN + c)*NPIX + (size_t)(hh*64 + r0)*128 + c0;
#pragma unroll
  for (int row = 0; row < 8; ++row) {
    int slot = (row + 4) % 5;
    f32x4 a = *(const f32x4*)&xs[(r0+row+4)*SD + c0];
    f32x4 b = *(const f32x4*)&xs[(r0+row+4)*SD + c0 + 4];
#pragma unroll
    for (int e = 0; e < 4; ++e) { w[slot][e] = a[e]; w[slot][4+e] = b[e]; }
    f32x4 acc = *(const f32x4*)(Xc + (size_t)row*128);
#pragma unroll
    for (int u = 0; u < 5; ++u)
#pragma unroll
      for (int v = 0; v < 5; ++v) {
        float pv = psf_s[u*5 + v];
#pragma unroll
        for (int p = 0; p < 4; ++p)
          acc[p] += pv * w[(row+u) % 5][p+v];
      }
    *(f32x4*)(Oc + (size_t)row*128) = acc;
  }
}

// ---------------------------------------------------------------------------
// k_pad: x_new -> zero-padded bf16 image, two copies (copy1 offset by one
// element so odd-v shifted reads are dword-aligned).
// ---------------------------------------------------------------------------
__global__ __launch_bounds__(256) void k_pad(const float* __restrict__ xn,
                                             float* __restrict__ ws) {
  ushort* xb0 = (ushort*)(ws + OFF_XB);
  ushort* xb1 = xb0 + XB0C;
  int ch = blockIdx.y;
  int idx = blockIdx.x*256 + threadIdx.x;
  if (ch == 0 && idx == 0) xb1[0] = 0;
  if (idx >= 136*136) return;
  int hp = idx / 136, wp = idx % 136;
  float v = 0.0f;
  if (hp >= 4 && hp < 132 && wp >= 4 && wp < 132)
    v = xn[(size_t)ch*NPIX + (hp-4)*128 + (wp-4)];
  __hip_bfloat16 b = __float2bfloat16(v);
  ushort bits = *(ushort*)&b;
  size_t o = (size_t)ch*18496 + idx;
  xb0[o] = bits;
  xb1[o + 1] = bits;
}

// ---------------------------------------------------------------------------
// k_gemm v8 (verified 44-46us; v9 dbuf and v10 32x32 both regressed).
// Bound by barrier-synchronized staging latency; staging decode
// (4 rows x 256B contiguous per instr) is the critical property.
// ---------------------------------------------------------------------------
__global__ __launch_bounds__(256, 3) void k_gemm(float* __restrict__ ws) {
  __shared__ __align__(16) ushort sA0[64*128];
  __shared__ __align__(16) ushort sA1[64*128];
  __shared__ __align__(16) ushort sB [64*128];

  const ushort* xb0 = (const ushort*)(ws + OFF_XB);
  const ushort* xb1 = xb0 + XB0C;
  int fid = blockIdx.x;
  int xcd = fid & 7, l = fid >> 3;        // l in [0,84)
  int nn = xcd & 3, hi = xcd >> 2;        // 2 XCDs per n; hi = sl parity
  int g = l % 21, m = l / 21;             // m in [0,4)
  int sl = m*2 + hi;                      // [0,8), K-slice of 2048

  int tid = threadIdx.x;
  int wv = tid >> 6, lane = tid & 63;
  int l16 = lane & 15, quad = lane >> 4;
  int lr = lane >> 4, lc = lane & 15;     // stage decode (4 rows x 16 cols)

  // shifts handled by this block
  int sidx0 = 2*g;
  int sidx1 = 2*g + 1;
  int sval1 = (sidx1 <= 40);
  if (sidx1 > 40) sidx1 = 40;
  int uv0 = sidx0 + 40, uv1 = sidx1 + 40;
  int u0 = uv0 / 9, v0 = uv0 % 9;
  int u1 = uv1 / 9, v1 = uv1 % 9;

  size_t chanBase = (size_t)(nn*64) * 18496;
  int ridx0 = sl * 16;                     // first image row of this K-slice
  // per-row-start pointers (element units), advanced by 136 per round
  const ushort* pB  = xb0 + chanBase + 548 + (size_t)ridx0*136;   // row 4, col 4
  size_t a0e = chanBase + (size_t)(u0 + ridx0)*136 + v0;
  size_t a1e = chanBase + (size_t)(u1 + ridx0)*136 + v1;
  const ushort* pA0 = (v0 & 1) ? (xb1 + a0e + 1) : (xb0 + a0e);
  const ushort* pA1 = (v1 & 1) ? (xb1 + a1e + 1) : (xb0 + a1e);

  f32x4 acc[2][4];
#pragma unroll
  for (int s = 0; s < 2; ++s)
#pragma unroll
    for (int jt = 0; jt < 4; ++jt) acc[s][jt] = (f32x4){0.f,0.f,0.f,0.f};

  for (int r = 0; r < 16; ++r) {
    if (r) __syncthreads();
    // ---- stage 3 tiles: wave wv covers rows wv*16 .. wv*16+15 ----
#pragma unroll
    for (int c = 0; c < 4; ++c) {
      int row = wv*16 + c*4 + lr;
      int sw = ((lc ^ (row & 15)) * 8);
      size_t goff = (size_t)row * 18496 + (size_t)lc * 8;
      {  // B: 8B-aligned source -> two uint2 loads
        const uint2* p = (const uint2*)(pB + goff);
        uint2 b0 = p[0], b1 = p[1];
        *(uint2*)&sB[row*128 + sw]     = b0;
        *(uint2*)&sB[row*128 + sw + 4] = b1;
      }
      {  // A0: 4B-aligned source -> four dword loads
        const uint* p = (const uint*)(pA0 + goff);
        uint4 v4; v4.x = p[0]; v4.y = p[1]; v4.z = p[2]; v4.w = p[3];
        *(uint4*)&sA0[row*128 + sw] = v4;
      }
      {  // A1
        const uint* p = (const uint*)(pA1 + goff);
        uint4 v4; v4.x = p[0]; v4.y = p[1]; v4.z = p[2]; v4.w = p[3];
        *(uint4*)&sA1[row*128 + sw] = v4;
      }
    }
    __syncthreads();
    // ---- compute 4 kt (K=32 each) ----
#pragma unroll
    for (int kt = 0; kt < 4; ++kt) {
      int c16 = kt*4 + quad;
      int sw = ((c16 ^ l16) * 8);
      bf16x8 af0 = *(const bf16x8*)&sA0[(wv*16 + l16)*128 + sw];
      bf16x8 af1 = *(const bf16x8*)&sA1[(wv*16 + l16)*128 + sw];
      bf16x8 bf[4];
#pragma unroll
      for (int jt = 0; jt < 4; ++jt)
        bf[jt] = *(const bf16x8*)&sB[(jt*16 + l16)*128 + sw];
#pragma unroll
      for (int jt = 0; jt < 4; ++jt) {
        acc[0][jt] = __builtin_amdgcn_mfma_f32_16x16x32_bf16(af0, bf[jt], acc[0][jt], 0, 0, 0);
        acc[1][jt] = __builtin_amdgcn_mfma_f32_16x16x32_bf16(af1, bf[jt], acc[1][jt], 0, 0, 0);
      }
    }
    pB += 136; pA0 += 136; pA1 += 136;
  }

  // ---- epilogue: plain vector stores into slice-private staging ----
  int io = wv*16 + quad*4;
  {
    float* dst = ws + OFF_RP + (((size_t)nn*8 + sl)*41 + sidx0)*4096;
#pragma unroll
    for (int jt = 0; jt < 4; ++jt) {
      int jout = jt*16 + l16;
      *reinterpret_cast<f32x4*>(dst + jout*64 + io) = acc[0][jt];
    }
  }
  if (sval1) {
    float* dst = ws + OFF_RP + (((size_t)nn*8 + sl)*41 + sidx1)*4096;
#pragma unroll
    for (int jt = 0; jt < 4; ++jt) {
      int jout = jt*16 + l16;
      *reinterpret_cast<f32x4*>(dst + jout*64 + io) = acc[1][jt];
    }
  }
}

// ---------------------------------------------------------------------------
// k_rsumtrans v3 (round 15): sum the 8 K-slices of plane (n,s) and write
// DIRECTLY into R [n][j][uv][i] — uv=40+s gets the plane (tile[j][i]),
// uv=40-s (s>0 only) gets its transpose (tile[i][j] via the padded LDS
// tile, same 2-way-free column read as the old PT generation). Eliminates
// the P/PT bounce (10.7 MB write + 10.6 MB re-read) and the k_rmerge
// launch. Global writes: 4 x 256B segments per instruction. Semantics
// identical to verified rsumtrans+rmerge chain (rounds 7-8).
// ---------------------------------------------------------------------------
__global__ __launch_bounds__(256) void k_rsumtrans(float* __restrict__ ws) {
  __shared__ float tile[64][65];
  int s = blockIdx.x, n = blockIdx.y;
  const float* base0 = ws + OFF_RP + ((size_t)n*8)*SLAB + (size_t)s*4096;
  float* Rn = ws + OFF_R + ((size_t)(n*64))*81*64;     // [j][uv][i]
  int t = threadIdx.x;
#pragma unroll
  for (int p = 0; p < 4; ++p) {
    int vidx = p*256 + t;                 // 0..1023, 16 f32x4 per plane row j
    int j = vidx >> 4, c0 = (vidx & 15)*4;
    f32x4 sum = (f32x4){0.f,0.f,0.f,0.f};
#pragma unroll
    for (int sl = 0; sl < 8; ++sl)
      sum += *(const f32x4*)(base0 + (size_t)sl*SLAB + j*64 + c0);
    tile[j][c0]   = sum[0]; tile[j][c0+1] = sum[1];
    tile[j][c0+2] = sum[2]; tile[j][c0+3] = sum[3];
    // uv = 40+s: R[j][40+s][i] = plane[j][i]
    *(f32x4*)(Rn + ((size_t)j*81 + (40 + s))*64 + c0) = sum;
  }
  if (s == 0) return;                     // uv=40 written once; no transpose twin
  __syncthreads();
#pragma unroll
  for (int p = 0; p < 4; ++p) {
    int vidx = p*256 + t;
    int j = vidx >> 4, c0 = (vidx & 15)*4;
    f32x4 o;
#pragma unroll
    for (int e = 0; e < 4; ++e) o[e] = tile[c0+e][j];
    // uv = 40-s: R[j][40-s][i] = plane[i][j]
    *(f32x4*)(Rn + ((size_t)j*81 + (40 - s))*64 + c0) = o;
  }
}

// ---------------------------------------------------------------------------
// k_pm v3: slab-staged sliding-window XtY (verified round 6).
// ---------------------------------------------------------------------------
__global__ __launch_bounds__(256) void k_pm(const float* __restrict__ xn,
                                            const float* __restrict__ y,
                                            float* __restrict__ ws) {
  __shared__ __align__(16) float xs[68*SD];
  __shared__ float red_s[4][25];
  int i = blockIdx.x, n = blockIdx.y, hh = blockIdx.z;
  int tid = threadIdx.x;
  const float* Xi = xn + (size_t)(n*CIN + i)*NPIX;
  int rbase = hh*64 - 2;
  for (int k = tid; k < 68*132; k += 256) {
    int R = k / 132, C = k - R*132;
    int hr = rbase + R, wc = C - 2;
    float v = 0.0f;
    if (hr >= 0 && hr < 128 && wc >= 0 && wc < 128) v = Xi[hr*128 + wc];
    xs[R*SD + C] = v;
  }
  __syncthreads();
  int cs = tid & 31, rs = tid >> 5;
  int c0 = cs*4, r0 = rs*8;
  float w[5][8];
#pragma unroll
  for (int k = 0; k < 4; ++k) {
    f32x4 a = *(const f32x4*)&xs[(r0+k)*SD + c0];
    f32x4 b = *(const f32x4*)&xs[(r0+k)*SD + c0 + 4];
#pragma unroll
    for (int e = 0; e < 4; ++e) { w[k][e] = a[e]; w[k][4+e] = b[e]; }
  }
  float acc[25];
#pragma unroll
  for (int t = 0; t < 25; ++t) acc[t] = 0.0f;
  const float* yp = y + (size_t)n*NPIX + (size_t)(hh*64 + r0)*128 + c0;
#pragma unroll
  for (int row = 0; row < 8; ++row) {
    int slot = (row + 4) % 5;
    f32x4 a = *(const f32x4*)&xs[(r0+row+4)*SD + c0];
    f32x4 b = *(const f32x4*)&xs[(r0+row+4)*SD + c0 + 4];
#pragma unroll
    for (int e = 0; e < 4; ++e) { w[slot][e] = a[e]; w[slot][4+e] = b[e]; }
    f32x4 yv = *(const f32x4*)(yp + (size_t)row*128);
#pragma unroll
    for (int u = 0; u < 5; ++u)
#pragma unroll
      for (int v = 0; v < 5; ++v) {
#pragma unroll
        for (int p = 0; p < 4; ++p)
          acc[u*5+v] += w[(row+u) % 5][p+v] * yv[p];
      }
  }
  int lane = tid & 63, wv = tid >> 6;
#pragma unroll
  for (int t = 0; t < 25; ++t) {
    float v = acc[t];
    WRED(v);
    if (lane == 0) red_s[wv][t] = v;
  }
  __syncthreads();
  if (tid < 25) {
    float s = red_s[0][tid] + red_s[1][tid] + red_s[2][tid] + red_s[3][tid];
    ws[OFF_PP + ((size_t)(hh*4 + n)*64 + i)*25 + tid] = s;
  }
}

// ---------------------------------------------------------------------------
// k_cg_first v2 (round 15): absorbs k_pm2. vv is computed inline from the
// PP partials + regularizer (identical arithmetic to the deleted k_pm2);
// j==0 blocks persist PV/RV for the subsequent cg_steps (launch boundary
// gives visibility). Everything after the vv load is verbatim.
// ---------------------------------------------------------------------------
__global__ __launch_bounds__(256) void k_cg_first(float* __restrict__ ws,
                                                  const float* __restrict__ dict,
                                                  const float* __restrict__ alpha_d,
                                                  const float* __restrict__ regp) {
  __shared__ float vv[MMAT];
  __shared__ float part[25][66];
  int n = blockIdx.y, j = blockIdx.x, tid = threadIdx.x;
  float reg = alpha_d[n] * 16384.0f * regp[0] * (1.0f/1600.0f);
  for (int t = tid; t < MMAT; t += 256) {
    int ii = t / 25, tt = t - ii*25;
    float s = ws[OFF_PP + ((size_t)(n)*64 + ii)*25 + tt]
            + ws[OFF_PP + ((size_t)(4 + n)*64 + ii)*25 + tt];
    float val = s + reg * dict[(n*CIN + ii)*25 + tt];
    vv[t] = val;
    if (j == 0) {
      ws[OFF_PV + n*MMAT + t] = val;
      ws[OFF_RV + n*MMAT + t] = val;
    }
  }
  __syncthreads();
  int i = tid & 63, qq = tid >> 6;
  const float* Rj = ws + OFF_R + ((size_t)(n*CIN + j))*81*64;
  const float* vi = &vv[i*25];
#pragma unroll
  for (int s6 = 0; s6 < 7; ++s6) {
    int ac = qq + 4*s6;
    if (ac < 25) {
      int a = ac/5, c = ac%5;
      float s = 0.0f;
#pragma unroll
      for (int b = 0; b < 5; ++b)
#pragma unroll
        for (int d = 0; d < 5; ++d)
          s += Rj[((4+b-a)*9 + (4+d-c))*64 + i] * vi[b*5+d];
      part[ac][i] = s;
    }
  }
  __syncthreads();
  float contrib = 0.0f;
  if (tid < 25) {
    float s = 0.0f;
    for (int t = 0; t < 64; ++t) s += part[tid][t];
    s += reg * vv[j*25 + tid];
    ws[OFF_AP + n*MMAT + j*25 + tid] = s;
    contrib = s * vv[j*25 + tid];
  }
  if (tid < 64) {
    WRED(contrib);
    if (tid == 0) ws[OFF_PAPP + 0*256 + n*64 + j] = contrib;
  }
}

// ---------------------------------------------------------------------------
// Fused CG step: full r in LDS; rr/alpha/beta in-block (identical across
// blocks); matvec A r_new; updates 25-elem segments; pAp partial per j.
// RV double-buffered by iteration parity -> race-free across blocks.
// ---------------------------------------------------------------------------
__global__ __launch_bounds__(256) void k_cg_step(float* __restrict__ ws, int it,
                                                 int last, float* __restrict__ out,
                                                 const float* __restrict__ alpha_d,
                                                 const float* __restrict__ regp) {
  __shared__ float vv[MMAT];       // r_new
  __shared__ float red_s[9];
  __shared__ float part[25][66];
  int n = blockIdx.y, j = blockIdx.x, tid = threadIdx.x;
  const float* rsrc = ws + ((it & 1) ? OFF_RV2 : OFF_RV) + n*MMAT;
  float*       rdst = ws + ((it & 1) ? OFF_RV  : OFF_RV2) + n*MMAT;
  int lane = tid & 63, wvi = tid >> 6;

  float rold[7], apv[7];
  float rrp = 0.0f;
#pragma unroll
  for (int t = 0; t < 7; ++t) {
    int idx = tid + 256*t;
    rold[t] = 0.0f; apv[t] = 0.0f;
    if (idx < MMAT) {
      rold[t] = rsrc[idx];
      apv[t]  = ws[OFF_AP + n*MMAT + idx];
      rrp += rold[t]*rold[t];
    }
  }
  WRED(rrp);
  if (lane == 0) red_s[wvi] = rrp;
  float pp = (tid < 64) ? ws[OFF_PAPP + it*256 + n*64 + tid] : 0.0f;
  if (tid < 64) { WRED(pp); if (tid == 0) red_s[4] = pp; }
  __syncthreads();
  float rr_old = red_s[0] + red_s[1] + red_s[2] + red_s[3];
  float alpha = rr_old / (red_s[4] + 1e-30f);

  if (last) {
    if (tid < 25) {
      int idx = n*MMAT + j*25 + tid;
      float dv = ws[OFF_DV + idx] + alpha * ws[OFF_PV + idx];
      out[4194304 + n*MMAT + j*25 + tid] = dv;
    }
    return;
  }

  float rrnp = 0.0f;
#pragma unroll
  for (int t = 0; t < 7; ++t) {
    int idx = tid + 256*t;
    if (idx < MMAT) {
      float rn = rold[t] - alpha * apv[t];
      vv[idx] = rn;
      rrnp += rn*rn;
    }
  }
  WRED(rrnp);
  __syncthreads();                           // vv complete
  if (lane == 0) red_s[5 + wvi] = rrnp;
  __syncthreads();
  float rr_new = red_s[5] + red_s[6] + red_s[7] + red_s[8];
  float beta = rr_new / (rr_old + 1e-30f);

  int i = tid & 63, qq = tid >> 6;
  const float* Rj = ws + OFF_R + ((size_t)(n*CIN + j))*81*64;
  const float* vi = &vv[i*25];
#pragma unroll
  for (int s6 = 0; s6 < 7; ++s6) {
    int ac = qq + 4*s6;
    if (ac < 25) {
      int a = ac/5, c = ac%5;
      float s = 0.0f;
#pragma unroll
      for (int b = 0; b < 5; ++b)
#pragma unroll
        for (int d = 0; d < 5; ++d)
          s += Rj[((4+b-a)*9 + (4+d-c))*64 + i] * vi[b*5+d];
      part[ac][i] = s;
    }
  }
  __syncthreads();
  float contrib = 0.0f;
  if (tid < 25) {
    float s = 0.0f;
    for (int t = 0; t < 64; ++t) s += part[tid][t];
    float reg = alpha_d[n] * 16384.0f * regp[0] * (1.0f/1600.0f);
    float rn_seg = vv[j*25 + tid];
    s += reg * rn_seg;
    int idx = n*MMAT + j*25 + tid;
    float p_old = ws[OFF_PV + idx];
    float dv = ws[OFF_DV + idx] + alpha * p_old;
    float pn  = rn_seg + beta * p_old;
    float apn = s + beta * ws[OFF_AP + idx];
    ws[OFF_DV + idx] = dv;
    ws[OFF_PV + idx] = pn;
    ws[OFF_AP + idx] = apn;
    rdst[j*25 + tid] = rn_seg;
    contrib = pn * apn;
  }
  if (tid < 64) {
    WRED(contrib);
    if (tid == 0) ws[OFF_PAPP + (it+1)*256 + n*64 + j] = contrib;
  }
}

// ---------------------------------------------------------------------------
extern "C" void kernel_launch(void* const* d_in, const int* in_sizes, int n_in,
                              void* d_out, int out_size, void* d_ws, size_t ws_size,
                              hipStream_t stream) {
  (void)in_sizes; (void)n_in; (void)out_size; (void)ws_size;
  const float* x    = (const float*)d_in[0];
  const float* dict = (const float*)d_in[1];
  const float* y    = (const float*)d_in[2];
  const float* ax   = (const float*)d_in[3];
  const float* ad   = (const float*)d_in[4];
  const float* regp = (const float*)d_in[5];
  float* out = (float*)d_out;
  float* ws  = (float*)d_ws;

  dim3 b256(256);
  k_sinv<<<dim3(33,4), b256, 0, stream>>>(dict, ax, ws);
  k_e<<<dim3(64,4,2), b256, 0, stream>>>(x, dict, ws);
  k_e2<<<dim3(64,4), b256, 0, stream>>>(y, ws);
  k_fft_rows<<<dim3(33,4), b256, 0, stream>>>(ws);
  k_fft_colpipe<<<dim3(65,4), dim3(128), 0, stream>>>(ws);
  k_ifft_rows<<<dim3(64,4), b256, 0, stream>>>(ws);
  k_xnew<<<dim3(64,4,2), b256, 0, stream>>>(x, dict, ws, out);

  // ---- R via MFMA: pad, LDS-staged shift-GEMM, slice-sum -> R direct
  k_pad<<<dim3(73,256), b256, 0, stream>>>(out, ws);
  k_gemm<<<dim3(672), b256, 0, stream>>>(ws);
  k_rsumtrans<<<dim3(41,4), b256, 0, stream>>>(ws);

  k_pm<<<dim3(64,4,2), b256, 0, stream>>>(out, y, ws);

  // ---- CG (cg_first absorbs pm2; NIT+1 launches) ----
  k_cg_first<<<dim3(64,4), b256, 0, stream>>>(ws, dict, ad, regp);
  for (int it = 0; it < NIT; ++it)
    k_cg_step<<<dim3(64,4), b256, 0, stream>>>(ws, it, (it == NIT-1) ? 1 : 0, out, ad, regp);
}